// Round 4
// baseline (13465.143 us; speedup 1.0000x reference)
//
#include <hip/hip_runtime.h>
#include <math.h>

// ---------------- workspace layout (float offsets), lifetime-packed ----------------
// Region R0 [0 .. 33.5M): A = [32,64,128,128] (enc h0; later tconv1 out)
//   During the middle phase (A dead), R0 hosts:
//     C : [32,256,32,32] = 8388608   at R0+0
//     D : [32,256,32,32] = 8388608   at R0+8388608   (VQ q = first 2097152)
//     E : [32,64,32,32]  = 2097152   at R0+16777216
// Region B [33.5M .. 50.3M): [32,128,64,64] = 16777216 (enc h1; later tconv0 out)
// Then codebook transpose/norms/counters and transposed weights.
// Peak total ~52.44M floats ~200 MiB (fits a 256 MiB workspace).
static const size_t A_OFF      = 0;
static const size_t C_OFF      = 0;
static const size_t D_OFF      = 8388608;
static const size_t E_OFF      = 16777216;
static const size_t B_OFF      = 33554432;
static const size_t CBT_OFF    = 50331648;  // 64*1024
static const size_t CNORM_OFF  = 50397184;  // 1024
static const size_t COUNTS_OFF = 50398208;  // 1024
static const size_t SUMSQ_OFF  = 50399232;  // 1 (+3 pad)
static const size_t WT_OFF     = 50399236;  // transposed weights (~2.03M floats)

// ---------------- small utility kernels ----------------
__global__ void k_zero(float* __restrict__ counts, float* __restrict__ sumsq) {
  const int t = blockIdx.x * 256 + threadIdx.x;
  if (t < 1024) counts[t] = 0.0f;
  if (t == 0) sumsq[0] = 0.0f;
}

// [Cout,Cin,K] -> [Cin,K,Cout]
__global__ void k_wt_conv(const float* __restrict__ w, float* __restrict__ wT,
                          int Cin, int Cout, int K) {
  const int n = Cin * Cout * K;
  for (int i = blockIdx.x * 256 + threadIdx.x; i < n; i += gridDim.x * 256) {
    const int co = i % Cout;
    const int k  = (i / Cout) % K;
    const int ci = i / (Cout * K);
    wT[i] = w[((size_t)co * Cin + ci) * K + k];
  }
}

// tconv weight [Cin,Cout,K] -> [Cin,K,Cout]
__global__ void k_wt_tconv(const float* __restrict__ w, float* __restrict__ wT,
                           int Cin, int Cout, int K) {
  const int n = Cin * Cout * K;
  for (int i = blockIdx.x * 256 + threadIdx.x; i < n; i += gridDim.x * 256) {
    const int co = i % Cout;
    const int k  = (i / Cout) % K;
    const int ci = i / (Cout * K);
    wT[i] = w[((size_t)ci * Cout + co) * K + k];
  }
}

// codebook [1024,64] -> cbT [64][1024] + cnorm[1024]
__global__ void k_cbt(const float* __restrict__ cb, float* __restrict__ cbT,
                      float* __restrict__ cnorm) {
  const int c = blockIdx.x * 256 + threadIdx.x;  // grid 4 x 256
  float s = 0.0f;
  for (int ci = 0; ci < 64; ++ci) {
    const float v = cb[(size_t)c * 64 + ci];
    s += v * v;
    cbT[(size_t)ci * 1024 + c] = v;
  }
  cnorm[c] = s;
}

// ---------------- conv 4x4 stride2 pad1, fused relu out ----------------
// out tile 32x32, 16 cout/block, thread: 4 px x 16 co
template <int CHUNK>
__global__ __launch_bounds__(256) void k_conv4s2(
    const float* __restrict__ in, const float* __restrict__ wT,
    const float* __restrict__ bias, float* __restrict__ out,
    int Cin, int Cout, int Ho, int Wo, int spw) {
  const int b   = blockIdx.z;
  const int co0 = blockIdx.y << 4;
  const int oy0 = (blockIdx.x / spw) << 5;
  const int ox0 = (blockIdx.x % spw) << 5;
  const int Hi = Ho << 1, Wi = Wo << 1;
  const int tid = threadIdx.x;
  const int ty = tid >> 4, tx = tid & 15;

  __shared__ float tin[CHUNK][66][67];

  float acc[4][16];
#pragma unroll
  for (int p = 0; p < 4; ++p)
#pragma unroll
    for (int co = 0; co < 16; ++co) acc[p][co] = 0.0f;

  const int iy0 = (oy0 << 1) - 1, ix0 = (ox0 << 1) - 1;

  for (int c0 = 0; c0 < Cin; c0 += CHUNK) {
    __syncthreads();
    for (int c = 0; c < CHUNK; ++c) {
      const float* ip = in + ((size_t)(b * Cin + c0 + c) * Hi) * Wi;
      for (int j = tid; j < 66 * 66; j += 256) {
        const int r = j / 66, col = j - r * 66;
        const int iy = iy0 + r, ix = ix0 + col;
        float v = 0.0f;
        if ((unsigned)iy < (unsigned)Hi && (unsigned)ix < (unsigned)Wi)
          v = ip[(size_t)iy * Wi + ix];
        tin[c][r][col] = v;
      }
    }
    __syncthreads();
#pragma unroll
    for (int c = 0; c < CHUNK; ++c) {
      const float* wp = wT + (size_t)(c0 + c) * 16 * Cout + co0;
#pragma unroll
      for (int ky = 0; ky < 4; ++ky)
#pragma unroll
        for (int kx = 0; kx < 4; ++kx) {
          const float v0 = tin[c][2 * ty + ky][2 * tx + kx];
          const float v1 = tin[c][2 * ty + ky][2 * tx + 32 + kx];
          const float v2 = tin[c][2 * ty + 32 + ky][2 * tx + kx];
          const float v3 = tin[c][2 * ty + 32 + ky][2 * tx + 32 + kx];
          const float* wk = wp + (ky * 4 + kx) * Cout;
#pragma unroll
          for (int co = 0; co < 16; ++co) {
            const float wv = wk[co];
            acc[0][co] = fmaf(v0, wv, acc[0][co]);
            acc[1][co] = fmaf(v1, wv, acc[1][co]);
            acc[2][co] = fmaf(v2, wv, acc[2][co]);
            acc[3][co] = fmaf(v3, wv, acc[3][co]);
          }
        }
    }
  }
#pragma unroll
  for (int co = 0; co < 16; ++co) {
    const float bv = bias[co0 + co];
    float* op = out + ((size_t)(b * Cout + co0 + co) * Ho) * Wo;
    op[(size_t)(oy0 + ty) * Wo + ox0 + tx]           = fmaxf(acc[0][co] + bv, 0.0f);
    op[(size_t)(oy0 + ty) * Wo + ox0 + tx + 16]      = fmaxf(acc[1][co] + bv, 0.0f);
    op[(size_t)(oy0 + ty + 16) * Wo + ox0 + tx]      = fmaxf(acc[2][co] + bv, 0.0f);
    op[(size_t)(oy0 + ty + 16) * Wo + ox0 + tx + 16] = fmaxf(acc[3][co] + bv, 0.0f);
  }
}

// ---------------- conv 3x3 pad1 (Cin=256 -> Cout=64, 32x32), relu on input ----------------
__global__ __launch_bounds__(256) void k_conv3x3(
    const float* __restrict__ in, const float* __restrict__ wT,
    const float* __restrict__ bias, float* __restrict__ out) {
  const int b   = blockIdx.y;
  const int co0 = blockIdx.x << 3;
  const int tid = threadIdx.x;
  const int ty = tid >> 4, tx = tid & 15;
  __shared__ float tin[8][34][35];
  float acc[4][8];
#pragma unroll
  for (int p = 0; p < 4; ++p)
#pragma unroll
    for (int co = 0; co < 8; ++co) acc[p][co] = 0.0f;

  for (int c0 = 0; c0 < 256; c0 += 8) {
    __syncthreads();
    for (int c = 0; c < 8; ++c) {
      const float* ip = in + (size_t)(b * 256 + c0 + c) * 1024;
      for (int j = tid; j < 34 * 34; j += 256) {
        const int r = j / 34, col = j - r * 34;
        const int iy = r - 1, ix = col - 1;
        float v = 0.0f;
        if ((unsigned)iy < 32u && (unsigned)ix < 32u) v = fmaxf(ip[iy * 32 + ix], 0.0f);
        tin[c][r][col] = v;
      }
    }
    __syncthreads();
#pragma unroll
    for (int c = 0; c < 8; ++c) {
#pragma unroll
      for (int dy = 0; dy < 3; ++dy)
#pragma unroll
        for (int dx = 0; dx < 3; ++dx) {
          const float v0 = tin[c][ty + dy][tx + dx];
          const float v1 = tin[c][ty + dy][tx + 16 + dx];
          const float v2 = tin[c][ty + 16 + dy][tx + dx];
          const float v3 = tin[c][ty + 16 + dy][tx + 16 + dx];
          const float* wk = wT + ((size_t)(c0 + c) * 9 + dy * 3 + dx) * 64 + co0;
#pragma unroll
          for (int co = 0; co < 8; ++co) {
            const float wv = wk[co];
            acc[0][co] = fmaf(v0, wv, acc[0][co]);
            acc[1][co] = fmaf(v1, wv, acc[1][co]);
            acc[2][co] = fmaf(v2, wv, acc[2][co]);
            acc[3][co] = fmaf(v3, wv, acc[3][co]);
          }
        }
    }
  }
#pragma unroll
  for (int co = 0; co < 8; ++co) {
    const float bv = bias[co0 + co];
    float* op = out + (size_t)(b * 64 + co0 + co) * 1024;
    op[(size_t)ty * 32 + tx]             = acc[0][co] + bv;
    op[(size_t)ty * 32 + tx + 16]        = acc[1][co] + bv;
    op[(size_t)(ty + 16) * 32 + tx]      = acc[2][co] + bv;
    op[(size_t)(ty + 16) * 32 + tx + 16] = acc[3][co] + bv;
  }
}

// ---------------- conv 1x1 (px-parallel), optional input relu / residual add ----------------
template <int IN_RELU, int HAS_RES>
__global__ __launch_bounds__(256) void k_conv1x1(
    const float* __restrict__ in, const float* __restrict__ wT,
    const float* __restrict__ bias, const float* __restrict__ res,
    float* __restrict__ out, int Cin, int Cout) {
  const int b   = blockIdx.y;
  const int co0 = blockIdx.x << 4;
  const int tid = threadIdx.x;
  const float* ip = in + (size_t)b * Cin * 1024 + tid;
  float acc[4][16];
#pragma unroll
  for (int p = 0; p < 4; ++p)
#pragma unroll
    for (int co = 0; co < 16; ++co) acc[p][co] = 0.0f;

#pragma unroll 4
  for (int ci = 0; ci < Cin; ++ci) {
    float v0 = ip[(size_t)ci * 1024];
    float v1 = ip[(size_t)ci * 1024 + 256];
    float v2 = ip[(size_t)ci * 1024 + 512];
    float v3 = ip[(size_t)ci * 1024 + 768];
    if (IN_RELU) {
      v0 = fmaxf(v0, 0.0f); v1 = fmaxf(v1, 0.0f);
      v2 = fmaxf(v2, 0.0f); v3 = fmaxf(v3, 0.0f);
    }
    const float* wp = wT + (size_t)ci * Cout + co0;
#pragma unroll
    for (int co = 0; co < 16; ++co) {
      const float wv = wp[co];
      acc[0][co] = fmaf(v0, wv, acc[0][co]);
      acc[1][co] = fmaf(v1, wv, acc[1][co]);
      acc[2][co] = fmaf(v2, wv, acc[2][co]);
      acc[3][co] = fmaf(v3, wv, acc[3][co]);
    }
  }
#pragma unroll
  for (int co = 0; co < 16; ++co) {
    const float bv = bias[co0 + co];
    const size_t o = (size_t)(b * Cout + co0 + co) * 1024 + tid;
    float r0 = acc[0][co] + bv, r1 = acc[1][co] + bv;
    float r2 = acc[2][co] + bv, r3 = acc[3][co] + bv;
    if (HAS_RES) {
      r0 += res[o]; r1 += res[o + 256]; r2 += res[o + 512]; r3 += res[o + 768];
    }
    out[o] = r0; out[o + 256] = r1; out[o + 512] = r2; out[o + 768] = r3;
  }
}

// ---------------- VQ: argmin + q gather + counts + sumsq ----------------
__global__ __launch_bounds__(256) void k_vq(
    const float* __restrict__ zlat, const float* __restrict__ cbT,
    const float* __restrict__ cnorm, const float* __restrict__ cb,
    float* __restrict__ q, float* __restrict__ counts, float* __restrict__ sumsq) {
  const int tid = threadIdx.x;
  const int px0 = blockIdx.x << 4;
  const int b   = px0 >> 10;
  const int pl0 = px0 & 1023;
  __shared__ float zT[64][17];
  __shared__ float rd[16][256];
  __shared__ int   ri[16][256];

  for (int j = tid; j < 1024; j += 256) {
    const int ci = j >> 4, p = j & 15;
    zT[ci][p] = zlat[(size_t)(b * 64 + ci) * 1024 + pl0 + p];
  }
  __syncthreads();

  float dot[4][16];
#pragma unroll
  for (int k = 0; k < 4; ++k)
#pragma unroll
    for (int p = 0; p < 16; ++p) dot[k][p] = 0.0f;

  for (int ci = 0; ci < 64; ++ci) {
    float z[16];
#pragma unroll
    for (int p = 0; p < 16; ++p) z[p] = zT[ci][p];
#pragma unroll
    for (int k = 0; k < 4; ++k) {
      const float cv = cbT[(size_t)ci * 1024 + (k << 8) + tid];
#pragma unroll
      for (int p = 0; p < 16; ++p) dot[k][p] = fmaf(cv, z[p], dot[k][p]);
    }
  }

  float bd[16]; int bi[16];
#pragma unroll
  for (int p = 0; p < 16; ++p) { bd[p] = 3.4e38f; bi[p] = 0; }
#pragma unroll
  for (int k = 0; k < 4; ++k) {
    const int c = (k << 8) + tid;
    const float cn = cnorm[c];
#pragma unroll
    for (int p = 0; p < 16; ++p) {
      const float d = cn - 2.0f * dot[k][p];
      if (d < bd[p]) { bd[p] = d; bi[p] = c; }  // k ascending => lowest idx kept on tie
    }
  }
#pragma unroll
  for (int p = 0; p < 16; ++p) { rd[p][tid] = bd[p]; ri[p][tid] = bi[p]; }
  __syncthreads();
  for (int s = 128; s >= 1; s >>= 1) {
    if (tid < s) {
#pragma unroll
      for (int p = 0; p < 16; ++p) {
        const float d2 = rd[p][tid + s]; const int i2 = ri[p][tid + s];
        const float d1 = rd[p][tid];     const int i1 = ri[p][tid];
        if (d2 < d1 || (d2 == d1 && i2 < i1)) { rd[p][tid] = d2; ri[p][tid] = i2; }
      }
    }
    __syncthreads();
  }
  if (tid < 16) atomicAdd(&counts[ri[tid][0]], 1.0f);

  const int p    = tid >> 4;
  const int best = ri[p][0];
  const int cb0  = (tid & 15) << 2;
  float ss = 0.0f;
  float* qp = q + (size_t)b * 65536 + pl0 + p;
#pragma unroll
  for (int cc = 0; cc < 4; ++cc) {
    const int ci = cb0 + cc;
    const float qv = cb[(size_t)best * 64 + ci];
    const float zv = zT[ci][p];
    const float df = qv - zv;
    ss += df * df;
    qp[(size_t)ci * 1024] = qv;
  }
#pragma unroll
  for (int o = 32; o > 0; o >>= 1) ss += __shfl_down(ss, o);
  if ((tid & 63) == 0) atomicAdd(sumsq, ss);
}

__global__ void k_final(const float* __restrict__ counts, const float* __restrict__ sumsq,
                        float* __restrict__ out2) {
  const int tid = threadIdx.x;
  float h = 0.0f;
  for (int k = tid; k < 1024; k += 256) {
    const float pr = counts[k] * (1.0f / 32768.0f);
    h -= pr * logf(pr + 1e-10f);
  }
#pragma unroll
  for (int o = 32; o > 0; o >>= 1) h += __shfl_down(h, o);
  __shared__ float hs[4];
  if ((tid & 63) == 0) hs[tid >> 6] = h;
  __syncthreads();
  if (tid == 0) {
    out2[0] = 1.25f * sumsq[0] * (1.0f / 2097152.0f);
    out2[1] = expf(hs[0] + hs[1] + hs[2] + hs[3]);
  }
}

// ---------------- transposed conv 4x4 stride2 pad1, phase-decomposed, relu out ----------------
template <int CHUNK>
__global__ __launch_bounds__(256) void k_tconv(
    const float* __restrict__ in, const float* __restrict__ wT,
    const float* __restrict__ bias, float* __restrict__ out,
    int Cin, int Cout, int Hi, int Wi, int rgw) {
  const int b     = blockIdx.z;
  const int phase = blockIdx.y & 3;
  const int ey = phase >> 1, ex = phase & 1;
  const int co0 = (blockIdx.y >> 2) << 4;
  const int Y0 = (blockIdx.x / rgw) << 5;
  const int X0 = (blockIdx.x % rgw) << 5;
  const int Ho = Hi << 1, Wo = Wi << 1;
  const int tid = threadIdx.x;
  const int ty = tid >> 4, tx = tid & 15;
  __shared__ float tin[CHUNK][34][35];
  float acc[4][16];
#pragma unroll
  for (int p = 0; p < 4; ++p)
#pragma unroll
    for (int co = 0; co < 16; ++co) acc[p][co] = 0.0f;

  const int khh = (1 - ey) * 4 + (1 - ex);
  const int khl = (1 - ey) * 4 + (3 - ex);
  const int klh = (3 - ey) * 4 + (1 - ex);
  const int kll = (3 - ey) * 4 + (3 - ex);

  for (int c0 = 0; c0 < Cin; c0 += CHUNK) {
    __syncthreads();
    for (int c = 0; c < CHUNK; ++c) {
      const float* ip = in + (size_t)(b * Cin + c0 + c) * Hi * Wi;
      for (int j = tid; j < 34 * 34; j += 256) {
        const int r = j / 34, col = j - r * 34;
        const int iy = Y0 - 1 + r, ix = X0 - 1 + col;
        float v = 0.0f;
        if ((unsigned)iy < (unsigned)Hi && (unsigned)ix < (unsigned)Wi)
          v = ip[(size_t)iy * Wi + ix];
        tin[c][r][col] = v;
      }
    }
    __syncthreads();
#pragma unroll
    for (int c = 0; c < CHUNK; ++c) {
      float vhh[4], vhl[4], vlh[4], vll[4];
#pragma unroll
      for (int p = 0; p < 4; ++p) {
        const int qy = ty + ((p >> 1) << 4);
        const int qx = tx + ((p & 1) << 4);
        vhh[p] = tin[c][qy + ey + 1][qx + ex + 1];
        vhl[p] = tin[c][qy + ey + 1][qx + ex];
        vlh[p] = tin[c][qy + ey][qx + ex + 1];
        vll[p] = tin[c][qy + ey][qx + ex];
      }
      const float* wc = wT + (size_t)(c0 + c) * 16 * Cout + co0;
#pragma unroll
      for (int co = 0; co < 16; ++co) {
        const float whh = wc[khh * Cout + co];
        const float whl = wc[khl * Cout + co];
        const float wlh = wc[klh * Cout + co];
        const float wll = wc[kll * Cout + co];
#pragma unroll
        for (int p = 0; p < 4; ++p) {
          acc[p][co] = fmaf(vhh[p], whh, acc[p][co]);
          acc[p][co] = fmaf(vhl[p], whl, acc[p][co]);
          acc[p][co] = fmaf(vlh[p], wlh, acc[p][co]);
          acc[p][co] = fmaf(vll[p], wll, acc[p][co]);
        }
      }
    }
  }
#pragma unroll
  for (int co = 0; co < 16; ++co) {
    const float bv = bias[co0 + co];
    float* op = out + (size_t)(b * Cout + co0 + co) * Ho * Wo;
#pragma unroll
    for (int p = 0; p < 4; ++p) {
      const int qy = ty + ((p >> 1) << 4);
      const int qx = tx + ((p & 1) << 4);
      const int oy = ((Y0 + qy) << 1) + ey;
      const int ox = ((X0 + qx) << 1) + ex;
      op[(size_t)oy * Wo + ox] = fmaxf(acc[p][co] + bv, 0.0f);
    }
  }
}

// ---------------- fused tconv2 (64->32, 128->256) + relu + 1x1 (32->3) ----------------
__global__ __launch_bounds__(256) void k_tconv2_out(
    const float* __restrict__ in, const float* __restrict__ wT,
    const float* __restrict__ tb, const float* __restrict__ ow,
    const float* __restrict__ ob, float* __restrict__ out) {
  const int b  = blockIdx.z;
  const int ey = blockIdx.y >> 1, ex = blockIdx.y & 1;
  const int Y0 = (blockIdx.x >> 3) << 4;
  const int X0 = (blockIdx.x & 7) << 4;
  const int tid = threadIdx.x;
  const int qy = tid >> 4, qx = tid & 15;
  __shared__ float tin[8][18][19];
  float acc[32];
#pragma unroll
  for (int co = 0; co < 32; ++co) acc[co] = 0.0f;

  const int khh = (1 - ey) * 4 + (1 - ex);
  const int khl = (1 - ey) * 4 + (3 - ex);
  const int klh = (3 - ey) * 4 + (1 - ex);
  const int kll = (3 - ey) * 4 + (3 - ex);

  for (int c0 = 0; c0 < 64; c0 += 8) {
    __syncthreads();
    for (int c = 0; c < 8; ++c) {
      const float* ip = in + (size_t)(b * 64 + c0 + c) * 16384;
      for (int j = tid; j < 18 * 18; j += 256) {
        const int r = j / 18, col = j - r * 18;
        const int iy = Y0 - 1 + r, ix = X0 - 1 + col;
        float v = 0.0f;
        if ((unsigned)iy < 128u && (unsigned)ix < 128u) v = ip[iy * 128 + ix];
        tin[c][r][col] = v;
      }
    }
    __syncthreads();
#pragma unroll
    for (int c = 0; c < 8; ++c) {
      const float vhh = tin[c][qy + ey + 1][qx + ex + 1];
      const float vhl = tin[c][qy + ey + 1][qx + ex];
      const float vlh = tin[c][qy + ey][qx + ex + 1];
      const float vll = tin[c][qy + ey][qx + ex];
      const float* wc = wT + (size_t)(c0 + c) * 16 * 32;
#pragma unroll
      for (int co = 0; co < 32; ++co) {
        acc[co] = fmaf(vhh, wc[khh * 32 + co], acc[co]);
        acc[co] = fmaf(vhl, wc[khl * 32 + co], acc[co]);
        acc[co] = fmaf(vlh, wc[klh * 32 + co], acc[co]);
        acc[co] = fmaf(vll, wc[kll * 32 + co], acc[co]);
      }
    }
  }
  const int oy = ((Y0 + qy) << 1) + ey;
  const int ox = ((X0 + qx) << 1) + ex;
#pragma unroll
  for (int co = 0; co < 32; ++co) acc[co] = fmaxf(acc[co] + tb[co], 0.0f);
#pragma unroll
  for (int c3 = 0; c3 < 3; ++c3) {
    float o = ob[c3];
#pragma unroll
    for (int co = 0; co < 32; ++co) o = fmaf(ow[c3 * 32 + co], acc[co], o);
    out[((size_t)(b * 3 + c3) * 256 + oy) * 256 + ox] = o;
  }
}

// ---------------- launcher ----------------
extern "C" void kernel_launch(void* const* d_in, const int* in_sizes, int n_in,
                              void* d_out, int out_size, void* d_ws, size_t ws_size,
                              hipStream_t stream) {
  const float* x        = (const float*)d_in[0];
  const float* enc_w0   = (const float*)d_in[1];
  const float* enc_b0   = (const float*)d_in[2];
  const float* enc_w1   = (const float*)d_in[3];
  const float* enc_b1   = (const float*)d_in[4];
  const float* enc_w2   = (const float*)d_in[5];
  const float* enc_b2   = (const float*)d_in[6];
  const float* er0w1    = (const float*)d_in[7];
  const float* er0b1    = (const float*)d_in[8];
  const float* er0w2    = (const float*)d_in[9];
  const float* er0b2    = (const float*)d_in[10];
  const float* er1w1    = (const float*)d_in[11];
  const float* er1b1    = (const float*)d_in[12];
  const float* er1w2    = (const float*)d_in[13];
  const float* er1b2    = (const float*)d_in[14];
  const float* eadj_w   = (const float*)d_in[15];
  const float* eadj_b   = (const float*)d_in[16];
  const float* codebook = (const float*)d_in[17];
  const float* dadj_w   = (const float*)d_in[18];
  const float* dadj_b   = (const float*)d_in[19];
  const float* dr0w1    = (const float*)d_in[20];
  const float* dr0b1    = (const float*)d_in[21];
  const float* dr0w2    = (const float*)d_in[22];
  const float* dr0b2    = (const float*)d_in[23];
  const float* dr1w1    = (const float*)d_in[24];
  const float* dr1b1    = (const float*)d_in[25];
  const float* dr1w2    = (const float*)d_in[26];
  const float* dr1b2    = (const float*)d_in[27];
  const float* tw0      = (const float*)d_in[28];
  const float* tb0      = (const float*)d_in[29];
  const float* tw1      = (const float*)d_in[30];
  const float* tb1      = (const float*)d_in[31];
  const float* tw2      = (const float*)d_in[32];
  const float* tb2      = (const float*)d_in[33];
  const float* out_w    = (const float*)d_in[34];
  const float* out_b    = (const float*)d_in[35];

  float* ws = (float*)d_ws;
  float* A      = ws + A_OFF;
  float* Bb     = ws + B_OFF;
  float* C      = ws + C_OFF;
  float* Dq     = ws + D_OFF;
  float* E      = ws + E_OFF;
  float* cbT    = ws + CBT_OFF;
  float* cnorm  = ws + CNORM_OFF;
  float* counts = ws + COUNTS_OFF;
  float* sumsq  = ws + SUMSQ_OFF;

  size_t o = WT_OFF;
  float* wt_enc0  = ws + o; o += (size_t)3 * 16 * 64;
  float* wt_enc1  = ws + o; o += (size_t)64 * 16 * 128;
  float* wt_enc2  = ws + o; o += (size_t)128 * 16 * 256;
  float* wt_er0w1 = ws + o; o += (size_t)256 * 9 * 64;
  float* wt_er0w2 = ws + o; o += (size_t)64 * 256;
  float* wt_er1w1 = ws + o; o += (size_t)256 * 9 * 64;
  float* wt_er1w2 = ws + o; o += (size_t)64 * 256;
  float* wt_eadj  = ws + o; o += (size_t)256 * 64;
  float* wt_dadj  = ws + o; o += (size_t)64 * 256;
  float* wt_dr0w1 = ws + o; o += (size_t)256 * 9 * 64;
  float* wt_dr0w2 = ws + o; o += (size_t)64 * 256;
  float* wt_dr1w1 = ws + o; o += (size_t)256 * 9 * 64;
  float* wt_dr1w2 = ws + o; o += (size_t)64 * 256;
  float* wt_t0    = ws + o; o += (size_t)256 * 16 * 128;
  float* wt_t1    = ws + o; o += (size_t)128 * 16 * 64;
  float* wt_t2    = ws + o; o += (size_t)64 * 16 * 32;

  float* fout = (float*)d_out;

  #define GB(n) (((n) + 255) / 256)
  k_zero<<<4, 256, 0, stream>>>(counts, sumsq);
  k_wt_conv<<<GB(3 * 64 * 16), 256, 0, stream>>>(enc_w0, wt_enc0, 3, 64, 16);
  k_wt_conv<<<GB(64 * 128 * 16), 256, 0, stream>>>(enc_w1, wt_enc1, 64, 128, 16);
  k_wt_conv<<<GB(128 * 256 * 16), 256, 0, stream>>>(enc_w2, wt_enc2, 128, 256, 16);
  k_wt_conv<<<GB(256 * 64 * 9), 256, 0, stream>>>(er0w1, wt_er0w1, 256, 64, 9);
  k_wt_conv<<<GB(64 * 256), 256, 0, stream>>>(er0w2, wt_er0w2, 64, 256, 1);
  k_wt_conv<<<GB(256 * 64 * 9), 256, 0, stream>>>(er1w1, wt_er1w1, 256, 64, 9);
  k_wt_conv<<<GB(64 * 256), 256, 0, stream>>>(er1w2, wt_er1w2, 64, 256, 1);
  k_wt_conv<<<GB(256 * 64), 256, 0, stream>>>(eadj_w, wt_eadj, 256, 64, 1);
  k_wt_conv<<<GB(64 * 256), 256, 0, stream>>>(dadj_w, wt_dadj, 64, 256, 1);
  k_wt_conv<<<GB(256 * 64 * 9), 256, 0, stream>>>(dr0w1, wt_dr0w1, 256, 64, 9);
  k_wt_conv<<<GB(64 * 256), 256, 0, stream>>>(dr0w2, wt_dr0w2, 64, 256, 1);
  k_wt_conv<<<GB(256 * 64 * 9), 256, 0, stream>>>(dr1w1, wt_dr1w1, 256, 64, 9);
  k_wt_conv<<<GB(64 * 256), 256, 0, stream>>>(dr1w2, wt_dr1w2, 64, 256, 1);
  k_wt_tconv<<<GB(256 * 128 * 16), 256, 0, stream>>>(tw0, wt_t0, 256, 128, 16);
  k_wt_tconv<<<GB(128 * 64 * 16), 256, 0, stream>>>(tw1, wt_t1, 128, 64, 16);
  k_wt_tconv<<<GB(64 * 32 * 16), 256, 0, stream>>>(tw2, wt_t2, 64, 32, 16);
  k_cbt<<<4, 256, 0, stream>>>(codebook, cbT, cnorm);

  // encoder
  k_conv4s2<3><<<dim3(16, 4, 32), 256, 0, stream>>>(x, wt_enc0, enc_b0, A, 3, 64, 128, 128, 4);
  k_conv4s2<2><<<dim3(4, 8, 32), 256, 0, stream>>>(A, wt_enc1, enc_b1, Bb, 64, 128, 64, 64, 2);
  k_conv4s2<2><<<dim3(1, 16, 32), 256, 0, stream>>>(Bb, wt_enc2, enc_b2, C, 128, 256, 32, 32, 1);
  k_conv3x3<<<dim3(8, 32), 256, 0, stream>>>(C, wt_er0w1, er0b1, E);
  k_conv1x1<1, 1><<<dim3(16, 32), 256, 0, stream>>>(E, wt_er0w2, er0b2, C, Dq, 64, 256);
  k_conv3x3<<<dim3(8, 32), 256, 0, stream>>>(Dq, wt_er1w1, er1b1, E);
  k_conv1x1<1, 1><<<dim3(16, 32), 256, 0, stream>>>(E, wt_er1w2, er1b2, Dq, C, 64, 256);
  k_conv1x1<0, 0><<<dim3(4, 32), 256, 0, stream>>>(C, wt_eadj, eadj_b, nullptr, E, 256, 64);
  // VQ (q -> first 2097152 floats of Dq)
  k_vq<<<2048, 256, 0, stream>>>(E, cbT, cnorm, codebook, Dq, counts, sumsq);
  // decoder
  k_conv1x1<0, 0><<<dim3(16, 32), 256, 0, stream>>>(Dq, wt_dadj, dadj_b, nullptr, C, 64, 256);
  k_conv3x3<<<dim3(8, 32), 256, 0, stream>>>(C, wt_dr0w1, dr0b1, E);
  k_conv1x1<1, 1><<<dim3(16, 32), 256, 0, stream>>>(E, wt_dr0w2, dr0b2, C, Dq, 64, 256);
  k_conv3x3<<<dim3(8, 32), 256, 0, stream>>>(Dq, wt_dr1w1, dr1b1, E);
  k_conv1x1<1, 1><<<dim3(16, 32), 256, 0, stream>>>(E, wt_dr1w2, dr1b2, Dq, C, 64, 256);
  k_tconv<8><<<dim3(1, 32, 32), 256, 0, stream>>>(C, wt_t0, tb0, Bb, 256, 128, 32, 32, 1);
  k_tconv<8><<<dim3(4, 16, 32), 256, 0, stream>>>(Bb, wt_t1, tb1, A, 128, 64, 64, 64, 2);
  k_tconv2_out<<<dim3(64, 4, 32), 256, 0, stream>>>(A, wt_t2, tb2, out_w, out_b, fout);
  k_final<<<1, 256, 0, stream>>>(counts, sumsq, fout + 6291456);
  #undef GB
}

// Round 5
// 3231.216 us; speedup vs baseline: 4.1672x; 4.1672x over previous
//
#include <hip/hip_runtime.h>
#include <math.h>

// ---------------- workspace layout (float offsets), lifetime-packed, PADDED activations ----
// A : [32][64][130][130] = 34,611,200  (enc0 out; later tconv1 out)       region [0, 34611200)
//   middle phase aliases into A region (A dead):
//     C : [32][256][34][34] = 9,469,952  at 0
//     D : [32][256][34][34] = 9,469,952  at 9,469,952
//     E : [32][64][32][32]  = 2,097,152  at 18,939,904   (dense, no pad)
//     Q : [32][64][1024]    = 2,097,152  at 21,037,056   (dense)
// B : [32][128][66][66] = 17,842,176  at 34,611,200  (enc1 out; later tconv0 out)
// smalls + transposed weights after B. Peak ~54.6M floats ~218 MB.
static const size_t A_OFF      = 0;
static const size_t C_OFF      = 0;
static const size_t D_OFF      = 9469952;
static const size_t E_OFF      = 18939904;
static const size_t Q_OFF      = 21037056;
static const size_t B_OFF      = 34611200;
static const size_t CBT_OFF    = 52453376;  // 64*1024
static const size_t CNORM_OFF  = 52518912;  // 1024
static const size_t COUNTS_OFF = 52519936;  // 1024
static const size_t SUMSQ_OFF  = 52520960;  // 1 (+3)
static const size_t WT_OFF     = 52520964;  // ~2.03M floats of transposed weights

// ---------------- weight transposes (unchanged layouts) ----------------
// [Cout,Cin,K] -> [Cin,K,Cout]
__global__ void k_wt_conv(const float* __restrict__ w, float* __restrict__ wT,
                          int Cin, int Cout, int K) {
  const int n = Cin * Cout * K;
  for (int i = blockIdx.x * 256 + threadIdx.x; i < n; i += gridDim.x * 256) {
    const int co = i % Cout;
    const int k  = (i / Cout) % K;
    const int ci = i / (Cout * K);
    wT[i] = w[((size_t)co * Cin + ci) * K + k];
  }
}
// tconv weight [Cin,Cout,K] -> [Cin,K,Cout]
__global__ void k_wt_tconv(const float* __restrict__ w, float* __restrict__ wT,
                           int Cin, int Cout, int K) {
  const int n = Cin * Cout * K;
  for (int i = blockIdx.x * 256 + threadIdx.x; i < n; i += gridDim.x * 256) {
    const int co = i % Cout;
    const int k  = (i / Cout) % K;
    const int ci = i / (Cout * K);
    wT[i] = w[((size_t)ci * Cout + co) * K + k];
  }
}
// codebook [1024,64] -> cbT [64][1024] + cnorm[1024]
__global__ void k_cbt(const float* __restrict__ cb, float* __restrict__ cbT,
                      float* __restrict__ cnorm) {
  const int c = blockIdx.x * 256 + threadIdx.x;
  float s = 0.0f;
  for (int ci = 0; ci < 64; ++ci) {
    const float v = cb[(size_t)c * 64 + ci];
    s += v * v;
    cbT[(size_t)ci * 1024 + c] = v;
  }
  cnorm[c] = s;
}

// ---------------- enc0: conv 4x4 s2 p1, Cin=3 (staged; only 2 barriers), PADDED out ----------
__global__ __launch_bounds__(256) void k_conv4s2_s3(
    const float* __restrict__ in, const float* __restrict__ wT,
    const float* __restrict__ bias, float* __restrict__ out) {
  const int b   = blockIdx.z;
  const int co0 = blockIdx.y << 4;
  const int oy0 = (blockIdx.x >> 2) << 5;
  const int ox0 = (blockIdx.x & 3) << 5;
  const int tid = threadIdx.x;
  const int ty = tid >> 4, tx = tid & 15;
  __shared__ float tin[3][66][67];
  float acc[4][16];
#pragma unroll
  for (int p = 0; p < 4; ++p)
#pragma unroll
    for (int co = 0; co < 16; ++co) acc[p][co] = 0.0f;

  const int iy0 = (oy0 << 1) - 1, ix0 = (ox0 << 1) - 1;
  for (int c = 0; c < 3; ++c) {
    const float* ip = in + (size_t)(b * 3 + c) * 65536;
    for (int j = tid; j < 66 * 66; j += 256) {
      const int r = j / 66, col = j - r * 66;
      const int iy = iy0 + r, ix = ix0 + col;
      float v = 0.0f;
      if ((unsigned)iy < 256u && (unsigned)ix < 256u) v = ip[iy * 256 + ix];
      tin[c][r][col] = v;
    }
  }
  __syncthreads();
#pragma unroll
  for (int c = 0; c < 3; ++c) {
    const float* wp = wT + (size_t)c * 16 * 64 + co0;
#pragma unroll
    for (int ky = 0; ky < 4; ++ky)
#pragma unroll
      for (int kx = 0; kx < 4; ++kx) {
        const float v0 = tin[c][2 * ty + ky][2 * tx + kx];
        const float v1 = tin[c][2 * ty + ky][2 * tx + 32 + kx];
        const float v2 = tin[c][2 * ty + 32 + ky][2 * tx + kx];
        const float v3 = tin[c][2 * ty + 32 + ky][2 * tx + 32 + kx];
        const float* wk = wp + (ky * 4 + kx) * 64;
#pragma unroll
        for (int co = 0; co < 16; ++co) {
          const float wv = wk[co];
          acc[0][co] = fmaf(v0, wv, acc[0][co]);
          acc[1][co] = fmaf(v1, wv, acc[1][co]);
          acc[2][co] = fmaf(v2, wv, acc[2][co]);
          acc[3][co] = fmaf(v3, wv, acc[3][co]);
        }
      }
  }
#pragma unroll
  for (int co = 0; co < 16; ++co) {
    const float bv = bias[co0 + co];
    float* op = out + (size_t)(b * 64 + co0 + co) * 16900;
    op[(size_t)(oy0 + ty + 1) * 130 + ox0 + tx + 1]        = fmaxf(acc[0][co] + bv, 0.0f);
    op[(size_t)(oy0 + ty + 1) * 130 + ox0 + tx + 17]       = fmaxf(acc[1][co] + bv, 0.0f);
    op[(size_t)(oy0 + ty + 17) * 130 + ox0 + tx + 1]       = fmaxf(acc[2][co] + bv, 0.0f);
    op[(size_t)(oy0 + ty + 17) * 130 + ox0 + tx + 17]      = fmaxf(acc[3][co] + bv, 0.0f);
  }
}

// ---------------- conv 4x4 s2 p1, px-parallel, padded in/out, relu out ----------------
template <int NCO>
__global__ __launch_bounds__(256) void k_conv4s2_px(
    const float* __restrict__ in, const float* __restrict__ wT,
    const float* __restrict__ bias, float* __restrict__ out,
    int Cin, int Cout, int woshift, int Wp, int instride, int Wop, int outstride) {
  const int b   = blockIdx.z;
  const int co0 = blockIdx.y * NCO;
  const int px  = blockIdx.x * 256 + threadIdx.x;
  const int y = px >> woshift, x = px - (y << woshift);
  const float* ip = in + (size_t)b * Cin * instride + (size_t)(2 * y) * Wp + 2 * x;
  float acc[NCO];
#pragma unroll
  for (int co = 0; co < NCO; ++co) acc[co] = 0.0f;
  const float* wp = wT + co0;
  for (int ci = 0; ci < Cin; ++ci) {
    float v[16];
#pragma unroll
    for (int ky = 0; ky < 4; ++ky)
#pragma unroll
      for (int kx = 0; kx < 4; ++kx) v[ky * 4 + kx] = ip[ky * Wp + kx];
    ip += instride;
    const float* wk = wp;
#pragma unroll
    for (int t = 0; t < 16; ++t) {
      const float vv = v[t];
#pragma unroll
      for (int co = 0; co < NCO; ++co) acc[co] = fmaf(vv, wk[co], acc[co]);
      wk += Cout;
    }
    wp += 16 * Cout;
  }
  float* op = out + (size_t)(b * Cout + co0) * outstride + (size_t)(y + 1) * Wop + (x + 1);
#pragma unroll
  for (int co = 0; co < NCO; ++co)
    op[(size_t)co * outstride] = fmaxf(acc[co] + bias[co0 + co], 0.0f);
}

// ---------------- conv3x3 p1 (256->64 @32x32), px-parallel, relu-on-input, dense out -------
__global__ __launch_bounds__(256) void k_conv3x3_px(
    const float* __restrict__ in, const float* __restrict__ wT,
    const float* __restrict__ bias, float* __restrict__ out) {
  const int b   = blockIdx.z;
  const int co0 = blockIdx.y << 4;
  const int px  = blockIdx.x * 256 + threadIdx.x;
  const int y = px >> 5, x = px & 31;
  const float* ip = in + (size_t)b * 256 * 1156 + (size_t)y * 34 + x;
  float acc[16];
#pragma unroll
  for (int co = 0; co < 16; ++co) acc[co] = 0.0f;
  const float* wp = wT + co0;
  for (int ci = 0; ci < 256; ++ci) {
    float v[9];
#pragma unroll
    for (int dy = 0; dy < 3; ++dy)
#pragma unroll
      for (int dx = 0; dx < 3; ++dx) v[dy * 3 + dx] = fmaxf(ip[dy * 34 + dx], 0.0f);
    ip += 1156;
    const float* wk = wp;
#pragma unroll
    for (int t = 0; t < 9; ++t) {
      const float vv = v[t];
#pragma unroll
      for (int co = 0; co < 16; ++co) acc[co] = fmaf(vv, wk[co], acc[co]);
      wk += 64;
    }
    wp += 9 * 64;
  }
  float* op = out + (size_t)(b * 64 + co0) * 1024 + px;
#pragma unroll
  for (int co = 0; co < 16; ++co) op[(size_t)co * 1024] = acc[co] + bias[co0 + co];
}

// ---------------- conv1x1 px-parallel; pad-aware in/out; optional relu / residual ----------
template <int IN_RELU, int HAS_RES, int IN_PAD, int OUT_PAD>
__global__ __launch_bounds__(256) void k_conv1x1_px(
    const float* __restrict__ in, const float* __restrict__ wT,
    const float* __restrict__ bias, const float* __restrict__ res,
    float* __restrict__ out, int Cin, int Cout) {
  const int b   = blockIdx.z;
  const int co0 = blockIdx.y << 4;
  const int px  = blockIdx.x * 256 + threadIdx.x;
  const int ppad = 35 + px + 2 * (px >> 5);
  const int ioff = IN_PAD ? ppad : px;
  const int istr = IN_PAD ? 1156 : 1024;
  const int ooff = OUT_PAD ? ppad : px;
  const int ostr = OUT_PAD ? 1156 : 1024;
  float acc[16];
#pragma unroll
  for (int co = 0; co < 16; ++co) acc[co] = 0.0f;
  const float* ip = in + (size_t)b * Cin * istr + ioff;
  const float* wp = wT + co0;
  for (int ci = 0; ci < Cin; ++ci) {
    float v = *ip;
    if (IN_RELU) v = fmaxf(v, 0.0f);
    ip += istr;
#pragma unroll
    for (int co = 0; co < 16; ++co) acc[co] = fmaf(v, wp[co], acc[co]);
    wp += Cout;
  }
  float* op = out + (size_t)(b * Cout + co0) * ostr + ooff;
  const float* rp = res + (size_t)(b * Cout + co0) * ostr + ooff;
#pragma unroll
  for (int co = 0; co < 16; ++co) {
    float r = acc[co] + bias[co0 + co];
    if (HAS_RES) r += rp[(size_t)co * ostr];
    op[(size_t)co * ostr] = r;
  }
}

// ---------------- tconv 4x4 s2 p1, px-parallel, phase-decomposed, padded in/out, relu ------
__global__ __launch_bounds__(256) void k_tconv_px(
    const float* __restrict__ in, const float* __restrict__ wT,
    const float* __restrict__ bias, float* __restrict__ out,
    int Cin, int Cout, int wshift, int Wp, int instride, int Wop, int outstride) {
  const int b     = blockIdx.z;
  const int phase = blockIdx.y & 3;
  const int ey = phase >> 1, ex = phase & 1;
  const int co0 = (blockIdx.y >> 2) << 5;
  const int px  = blockIdx.x * 256 + threadIdx.x;
  const int y = px >> wshift, x = px - (y << wshift);
  const float* ip = in + (size_t)b * Cin * instride + (size_t)(y + ey) * Wp + (x + ex);
  const int kll = (3 - ey) * 4 + (3 - ex);
  const int klh = (3 - ey) * 4 + (1 - ex);
  const int khl = (1 - ey) * 4 + (3 - ex);
  const int khh = (1 - ey) * 4 + (1 - ex);
  float acc[32];
#pragma unroll
  for (int co = 0; co < 32; ++co) acc[co] = 0.0f;
  const float* wp = wT + co0;
#pragma unroll 2
  for (int ci = 0; ci < Cin; ++ci) {
    const float vll = ip[0];
    const float vlh = ip[1];
    const float vhl = ip[Wp];
    const float vhh = ip[Wp + 1];
    ip += instride;
    const float* w0 = wp + kll * Cout;
    const float* w1 = wp + klh * Cout;
    const float* w2 = wp + khl * Cout;
    const float* w3 = wp + khh * Cout;
#pragma unroll
    for (int co = 0; co < 32; ++co) {
      float a = acc[co];
      a = fmaf(vll, w0[co], a);
      a = fmaf(vlh, w1[co], a);
      a = fmaf(vhl, w2[co], a);
      a = fmaf(vhh, w3[co], a);
      acc[co] = a;
    }
    wp += 16 * Cout;
  }
  const int oy = 2 * y + ey, ox = 2 * x + ex;
  float* op = out + (size_t)(b * Cout + co0) * outstride + (size_t)(oy + 1) * Wop + (ox + 1);
#pragma unroll
  for (int co = 0; co < 32; ++co)
    op[(size_t)co * outstride] = fmaxf(acc[co] + bias[co0 + co], 0.0f);
}

// ---------------- fused tconv2 (64->32, 128->256) + relu + 1x1 (32->3), px-parallel --------
__global__ __launch_bounds__(256) void k_tconv2_out_px(
    const float* __restrict__ in, const float* __restrict__ wT,
    const float* __restrict__ tb, const float* __restrict__ ow,
    const float* __restrict__ ob, float* __restrict__ out) {
  const int b  = blockIdx.z;
  const int ey = blockIdx.y >> 1, ex = blockIdx.y & 1;
  const int px = blockIdx.x * 256 + threadIdx.x;
  const int y = px >> 7, x = px & 127;
  const float* ip = in + (size_t)b * 64 * 16900 + (size_t)(y + ey) * 130 + (x + ex);
  const int kll = (3 - ey) * 4 + (3 - ex);
  const int klh = (3 - ey) * 4 + (1 - ex);
  const int khl = (1 - ey) * 4 + (3 - ex);
  const int khh = (1 - ey) * 4 + (1 - ex);
  float acc[32];
#pragma unroll
  for (int co = 0; co < 32; ++co) acc[co] = 0.0f;
  const float* wp = wT;
#pragma unroll 2
  for (int ci = 0; ci < 64; ++ci) {
    const float vll = ip[0];
    const float vlh = ip[1];
    const float vhl = ip[130];
    const float vhh = ip[131];
    ip += 16900;
    const float* w0 = wp + kll * 32;
    const float* w1 = wp + klh * 32;
    const float* w2 = wp + khl * 32;
    const float* w3 = wp + khh * 32;
#pragma unroll
    for (int co = 0; co < 32; ++co) {
      float a = acc[co];
      a = fmaf(vll, w0[co], a);
      a = fmaf(vlh, w1[co], a);
      a = fmaf(vhl, w2[co], a);
      a = fmaf(vhh, w3[co], a);
      acc[co] = a;
    }
    wp += 16 * 32;
  }
#pragma unroll
  for (int co = 0; co < 32; ++co) acc[co] = fmaxf(acc[co] + tb[co], 0.0f);
  const int oy = 2 * y + ey, ox = 2 * x + ex;
#pragma unroll
  for (int c3 = 0; c3 < 3; ++c3) {
    float o = ob[c3];
#pragma unroll
    for (int co = 0; co < 32; ++co) o = fmaf(ow[c3 * 32 + co], acc[co], o);
    out[((size_t)(b * 3 + c3) * 256 + oy) * 256 + ox] = o;
  }
}

// ---------------- VQ: argmin + q gather + counts + sumsq (unchanged) ----------------
__global__ __launch_bounds__(256) void k_vq(
    const float* __restrict__ zlat, const float* __restrict__ cbT,
    const float* __restrict__ cnorm, const float* __restrict__ cb,
    float* __restrict__ q, float* __restrict__ counts, float* __restrict__ sumsq) {
  const int tid = threadIdx.x;
  const int px0 = blockIdx.x << 4;
  const int b   = px0 >> 10;
  const int pl0 = px0 & 1023;
  __shared__ float zT[64][17];
  __shared__ float rd[16][256];
  __shared__ int   ri[16][256];
  for (int j = tid; j < 1024; j += 256) {
    const int ci = j >> 4, p = j & 15;
    zT[ci][p] = zlat[(size_t)(b * 64 + ci) * 1024 + pl0 + p];
  }
  __syncthreads();
  float dot[4][16];
#pragma unroll
  for (int k = 0; k < 4; ++k)
#pragma unroll
    for (int p = 0; p < 16; ++p) dot[k][p] = 0.0f;
  for (int ci = 0; ci < 64; ++ci) {
    float z[16];
#pragma unroll
    for (int p = 0; p < 16; ++p) z[p] = zT[ci][p];
#pragma unroll
    for (int k = 0; k < 4; ++k) {
      const float cv = cbT[(size_t)ci * 1024 + (k << 8) + tid];
#pragma unroll
      for (int p = 0; p < 16; ++p) dot[k][p] = fmaf(cv, z[p], dot[k][p]);
    }
  }
  float bd[16]; int bi[16];
#pragma unroll
  for (int p = 0; p < 16; ++p) { bd[p] = 3.4e38f; bi[p] = 0; }
#pragma unroll
  for (int k = 0; k < 4; ++k) {
    const int c = (k << 8) + tid;
    const float cn = cnorm[c];
#pragma unroll
    for (int p = 0; p < 16; ++p) {
      const float d = cn - 2.0f * dot[k][p];
      if (d < bd[p]) { bd[p] = d; bi[p] = c; }
    }
  }
#pragma unroll
  for (int p = 0; p < 16; ++p) { rd[p][tid] = bd[p]; ri[p][tid] = bi[p]; }
  __syncthreads();
  for (int s = 128; s >= 1; s >>= 1) {
    if (tid < s) {
#pragma unroll
      for (int p = 0; p < 16; ++p) {
        const float d2 = rd[p][tid + s]; const int i2 = ri[p][tid + s];
        const float d1 = rd[p][tid];     const int i1 = ri[p][tid];
        if (d2 < d1 || (d2 == d1 && i2 < i1)) { rd[p][tid] = d2; ri[p][tid] = i2; }
      }
    }
    __syncthreads();
  }
  if (tid < 16) atomicAdd(&counts[ri[tid][0]], 1.0f);
  const int p    = tid >> 4;
  const int best = ri[p][0];
  const int cb0  = (tid & 15) << 2;
  float ss = 0.0f;
  float* qp = q + (size_t)b * 65536 + pl0 + p;
#pragma unroll
  for (int cc = 0; cc < 4; ++cc) {
    const int ci = cb0 + cc;
    const float qv = cb[(size_t)best * 64 + ci];
    const float zv = zT[ci][p];
    const float df = qv - zv;
    ss += df * df;
    qp[(size_t)ci * 1024] = qv;
  }
#pragma unroll
  for (int o = 32; o > 0; o >>= 1) ss += __shfl_down(ss, o);
  if ((tid & 63) == 0) atomicAdd(sumsq, ss);
}

__global__ void k_final(const float* __restrict__ counts, const float* __restrict__ sumsq,
                        float* __restrict__ out2) {
  const int tid = threadIdx.x;
  float h = 0.0f;
  for (int k = tid; k < 1024; k += 256) {
    const float pr = counts[k] * (1.0f / 32768.0f);
    h -= pr * logf(pr + 1e-10f);
  }
#pragma unroll
  for (int o = 32; o > 0; o >>= 1) h += __shfl_down(h, o);
  __shared__ float hs[4];
  if ((tid & 63) == 0) hs[tid >> 6] = h;
  __syncthreads();
  if (tid == 0) {
    out2[0] = 1.25f * sumsq[0] * (1.0f / 2097152.0f);
    out2[1] = expf(hs[0] + hs[1] + hs[2] + hs[3]);
  }
}

// ---------------- launcher ----------------
extern "C" void kernel_launch(void* const* d_in, const int* in_sizes, int n_in,
                              void* d_out, int out_size, void* d_ws, size_t ws_size,
                              hipStream_t stream) {
  const float* x        = (const float*)d_in[0];
  const float* enc_w0   = (const float*)d_in[1];
  const float* enc_b0   = (const float*)d_in[2];
  const float* enc_w1   = (const float*)d_in[3];
  const float* enc_b1   = (const float*)d_in[4];
  const float* enc_w2   = (const float*)d_in[5];
  const float* enc_b2   = (const float*)d_in[6];
  const float* er0w1    = (const float*)d_in[7];
  const float* er0b1    = (const float*)d_in[8];
  const float* er0w2    = (const float*)d_in[9];
  const float* er0b2    = (const float*)d_in[10];
  const float* er1w1    = (const float*)d_in[11];
  const float* er1b1    = (const float*)d_in[12];
  const float* er1w2    = (const float*)d_in[13];
  const float* er1b2    = (const float*)d_in[14];
  const float* eadj_w   = (const float*)d_in[15];
  const float* eadj_b   = (const float*)d_in[16];
  const float* codebook = (const float*)d_in[17];
  const float* dadj_w   = (const float*)d_in[18];
  const float* dadj_b   = (const float*)d_in[19];
  const float* dr0w1    = (const float*)d_in[20];
  const float* dr0b1    = (const float*)d_in[21];
  const float* dr0w2    = (const float*)d_in[22];
  const float* dr0b2    = (const float*)d_in[23];
  const float* dr1w1    = (const float*)d_in[24];
  const float* dr1b1    = (const float*)d_in[25];
  const float* dr1w2    = (const float*)d_in[26];
  const float* dr1b2    = (const float*)d_in[27];
  const float* tw0      = (const float*)d_in[28];
  const float* tb0      = (const float*)d_in[29];
  const float* tw1      = (const float*)d_in[30];
  const float* tb1      = (const float*)d_in[31];
  const float* tw2      = (const float*)d_in[32];
  const float* tb2      = (const float*)d_in[33];
  const float* out_w    = (const float*)d_in[34];
  const float* out_b    = (const float*)d_in[35];

  float* ws = (float*)d_ws;
  float* A      = ws + A_OFF;
  float* Bb     = ws + B_OFF;
  float* C      = ws + C_OFF;
  float* Dq     = ws + D_OFF;
  float* E      = ws + E_OFF;
  float* Q      = ws + Q_OFF;
  float* cbT    = ws + CBT_OFF;
  float* cnorm  = ws + CNORM_OFF;
  float* counts = ws + COUNTS_OFF;
  float* sumsq  = ws + SUMSQ_OFF;

  size_t o = WT_OFF;
  float* wt_enc0  = ws + o; o += (size_t)3 * 16 * 64;
  float* wt_enc1  = ws + o; o += (size_t)64 * 16 * 128;
  float* wt_enc2  = ws + o; o += (size_t)128 * 16 * 256;
  float* wt_er0w1 = ws + o; o += (size_t)256 * 9 * 64;
  float* wt_er0w2 = ws + o; o += (size_t)64 * 256;
  float* wt_er1w1 = ws + o; o += (size_t)256 * 9 * 64;
  float* wt_er1w2 = ws + o; o += (size_t)64 * 256;
  float* wt_eadj  = ws + o; o += (size_t)256 * 64;
  float* wt_dadj  = ws + o; o += (size_t)64 * 256;
  float* wt_dr0w1 = ws + o; o += (size_t)256 * 9 * 64;
  float* wt_dr0w2 = ws + o; o += (size_t)64 * 256;
  float* wt_dr1w1 = ws + o; o += (size_t)256 * 9 * 64;
  float* wt_dr1w2 = ws + o; o += (size_t)64 * 256;
  float* wt_t0    = ws + o; o += (size_t)256 * 16 * 128;
  float* wt_t1    = ws + o; o += (size_t)128 * 16 * 64;
  float* wt_t2    = ws + o; o += (size_t)64 * 16 * 32;

  float* fout = (float*)d_out;

  #define GB(n) (((n) + 255) / 256)
  // halo/counter zeroing #1: whole activation+smalls region
  hipMemsetAsync(ws, 0, WT_OFF * sizeof(float), stream);

  k_wt_conv<<<GB(3 * 64 * 16), 256, 0, stream>>>(enc_w0, wt_enc0, 3, 64, 16);
  k_wt_conv<<<GB(64 * 128 * 16), 256, 0, stream>>>(enc_w1, wt_enc1, 64, 128, 16);
  k_wt_conv<<<GB(128 * 256 * 16), 256, 0, stream>>>(enc_w2, wt_enc2, 128, 256, 16);
  k_wt_conv<<<GB(256 * 64 * 9), 256, 0, stream>>>(er0w1, wt_er0w1, 256, 64, 9);
  k_wt_conv<<<GB(64 * 256), 256, 0, stream>>>(er0w2, wt_er0w2, 64, 256, 1);
  k_wt_conv<<<GB(256 * 64 * 9), 256, 0, stream>>>(er1w1, wt_er1w1, 256, 64, 9);
  k_wt_conv<<<GB(64 * 256), 256, 0, stream>>>(er1w2, wt_er1w2, 64, 256, 1);
  k_wt_conv<<<GB(256 * 64), 256, 0, stream>>>(eadj_w, wt_eadj, 256, 64, 1);
  k_wt_conv<<<GB(64 * 256), 256, 0, stream>>>(dadj_w, wt_dadj, 64, 256, 1);
  k_wt_conv<<<GB(256 * 64 * 9), 256, 0, stream>>>(dr0w1, wt_dr0w1, 256, 64, 9);
  k_wt_conv<<<GB(64 * 256), 256, 0, stream>>>(dr0w2, wt_dr0w2, 64, 256, 1);
  k_wt_conv<<<GB(256 * 64 * 9), 256, 0, stream>>>(dr1w1, wt_dr1w1, 256, 64, 9);
  k_wt_conv<<<GB(64 * 256), 256, 0, stream>>>(dr1w2, wt_dr1w2, 64, 256, 1);
  k_wt_tconv<<<GB(256 * 128 * 16), 256, 0, stream>>>(tw0, wt_t0, 256, 128, 16);
  k_wt_tconv<<<GB(128 * 64 * 16), 256, 0, stream>>>(tw1, wt_t1, 128, 64, 16);
  k_wt_tconv<<<GB(64 * 32 * 16), 256, 0, stream>>>(tw2, wt_t2, 64, 32, 16);
  k_cbt<<<4, 256, 0, stream>>>(codebook, cbT, cnorm);

  // ---------- encoder ----------
  k_conv4s2_s3<<<dim3(16, 4, 32), 256, 0, stream>>>(x, wt_enc0, enc_b0, A);
  k_conv4s2_px<32><<<dim3(16, 4, 32), 256, 0, stream>>>(A, wt_enc1, enc_b1, Bb,
                                                        64, 128, 6, 130, 16900, 66, 4356);
  // A now dead -> zero C+D region (halos for enc2/res outputs)
  hipMemsetAsync(ws, 0, (size_t)18939904 * sizeof(float), stream);
  k_conv4s2_px<32><<<dim3(4, 8, 32), 256, 0, stream>>>(Bb, wt_enc2, enc_b2, C,
                                                       128, 256, 5, 66, 4356, 34, 1156);
  k_conv3x3_px<<<dim3(4, 4, 32), 256, 0, stream>>>(C, wt_er0w1, er0b1, E);
  k_conv1x1_px<1, 1, 0, 1><<<dim3(4, 16, 32), 256, 0, stream>>>(E, wt_er0w2, er0b2, C, Dq, 64, 256);
  k_conv3x3_px<<<dim3(4, 4, 32), 256, 0, stream>>>(Dq, wt_er1w1, er1b1, E);
  k_conv1x1_px<1, 1, 0, 1><<<dim3(4, 16, 32), 256, 0, stream>>>(E, wt_er1w2, er1b2, Dq, C, 64, 256);
  k_conv1x1_px<0, 0, 1, 0><<<dim3(4, 4, 32), 256, 0, stream>>>(C, wt_eadj, eadj_b, nullptr, E, 256, 64);
  // ---------- VQ ----------
  k_vq<<<2048, 256, 0, stream>>>(E, cbT, cnorm, codebook, Q, counts, sumsq);
  // ---------- decoder ----------
  k_conv1x1_px<0, 0, 0, 1><<<dim3(4, 16, 32), 256, 0, stream>>>(Q, wt_dadj, dadj_b, nullptr, C, 64, 256);
  k_conv3x3_px<<<dim3(4, 4, 32), 256, 0, stream>>>(C, wt_dr0w1, dr0b1, E);
  k_conv1x1_px<1, 1, 0, 1><<<dim3(4, 16, 32), 256, 0, stream>>>(E, wt_dr0w2, dr0b2, C, Dq, 64, 256);
  k_conv3x3_px<<<dim3(4, 4, 32), 256, 0, stream>>>(Dq, wt_dr1w1, dr1b1, E);
  k_conv1x1_px<1, 1, 0, 1><<<dim3(4, 16, 32), 256, 0, stream>>>(E, wt_dr1w2, dr1b2, Dq, C, 64, 256);
  k_tconv_px<<<dim3(4, 16, 32), 256, 0, stream>>>(C, wt_t0, tb0, Bb,
                                                  256, 128, 5, 34, 1156, 66, 4356);
  // C/D/E/Q dead -> zero A region (halos for tconv1 output)
  hipMemsetAsync(ws, 0, (size_t)34611200 * sizeof(float), stream);
  k_tconv_px<<<dim3(16, 8, 32), 256, 0, stream>>>(Bb, wt_t1, tb1, A,
                                                  128, 64, 6, 66, 4356, 130, 16900);
  k_tconv2_out_px<<<dim3(64, 4, 32), 256, 0, stream>>>(A, wt_t2, tb2, out_w, out_b, fout);
  k_final<<<1, 256, 0, stream>>>(counts, sumsq, fout + 6291456);
  #undef GB
}

// Round 6
// 2659.997 us; speedup vs baseline: 5.0621x; 1.2147x over previous
//
#include <hip/hip_runtime.h>
#include <math.h>

typedef __attribute__((ext_vector_type(4))) float f32x4;
typedef __attribute__((ext_vector_type(8))) short short8;
typedef __attribute__((ext_vector_type(4))) unsigned int u32x4;
typedef unsigned short ushort_t;
typedef unsigned int uint_t;

// ---------------- workspace layout (float offsets), lifetime-packed, PADDED activations ----
static const size_t A_OFF      = 0;
static const size_t C_OFF      = 0;
static const size_t D_OFF      = 9469952;
static const size_t E_OFF      = 18939904;
static const size_t Q_OFF      = 21037056;
static const size_t B_OFF      = 34611200;
static const size_t CBT_OFF    = 52453376;  // 64*1024
static const size_t CNORM_OFF  = 52518912;  // 1024
static const size_t COUNTS_OFF = 52519936;  // 1024
static const size_t SUMSQ_OFF  = 52520960;  // 1 (+3)
static const size_t WT_OFF     = 52520964;  // fp32 transposed weights, then bf16 tconv weights

__device__ __forceinline__ ushort_t f2b(float f) {
  uint_t u = __float_as_uint(f);
  uint_t r = (u + 0x7FFFu + ((u >> 16) & 1u)) >> 16;
  return (ushort_t)r;
}

// ---------------- weight transposes ----------------
// [Cout,Cin,K] -> [Cin,K,Cout]
__global__ void k_wt_conv(const float* __restrict__ w, float* __restrict__ wT,
                          int Cin, int Cout, int K) {
  const int n = Cin * Cout * K;
  for (int i = blockIdx.x * 256 + threadIdx.x; i < n; i += gridDim.x * 256) {
    const int co = i % Cout;
    const int k  = (i / Cout) % K;
    const int ci = i / (Cout * K);
    wT[i] = w[((size_t)co * Cin + ci) * K + k];
  }
}
// tconv weight [Cin][Cout][16] -> bf16 wbT[phase][co][ci*4+tap]
// tap=(ty,tx): kidx = (3-2*ty-ey)*4 + (3-2*tx-ex)
__global__ void k_wtb(const float* __restrict__ w, ushort_t* __restrict__ wbT,
                      int Cin, int Cout) {
  const int n = 4 * Cout * Cin * 4;
  for (int i = blockIdx.x * 256 + threadIdx.x; i < n; i += gridDim.x * 256) {
    const int tap = i & 3;
    const int ci  = (i >> 2) % Cin;
    const int co  = ((i >> 2) / Cin) % Cout;
    const int ph  = (i >> 2) / (Cin * Cout);
    const int ey = ph >> 1, ex = ph & 1;
    const int ty = tap >> 1, tx = tap & 1;
    const int kidx = (3 - 2 * ty - ey) * 4 + (3 - 2 * tx - ex);
    wbT[i] = f2b(w[((size_t)ci * Cout + co) * 16 + kidx]);
  }
}
// codebook [1024,64] -> cbT [64][1024] + cnorm[1024]
__global__ void k_cbt(const float* __restrict__ cb, float* __restrict__ cbT,
                      float* __restrict__ cnorm) {
  const int c = blockIdx.x * 256 + threadIdx.x;
  float s = 0.0f;
  for (int ci = 0; ci < 64; ++ci) {
    const float v = cb[(size_t)c * 64 + ci];
    s += v * v;
    cbT[(size_t)ci * 1024 + c] = v;
  }
  cnorm[c] = s;
}

// ---------------- enc0: conv 4x4 s2 p1, Cin=3, staged, PADDED out ----------
__global__ __launch_bounds__(256) void k_conv4s2_s3(
    const float* __restrict__ in, const float* __restrict__ wT,
    const float* __restrict__ bias, float* __restrict__ out) {
  const int b   = blockIdx.z;
  const int co0 = blockIdx.y << 4;
  const int oy0 = (blockIdx.x >> 2) << 5;
  const int ox0 = (blockIdx.x & 3) << 5;
  const int tid = threadIdx.x;
  const int ty = tid >> 4, tx = tid & 15;
  __shared__ float tin[3][66][67];
  float acc[4][16];
#pragma unroll
  for (int p = 0; p < 4; ++p)
#pragma unroll
    for (int co = 0; co < 16; ++co) acc[p][co] = 0.0f;

  const int iy0 = (oy0 << 1) - 1, ix0 = (ox0 << 1) - 1;
  for (int c = 0; c < 3; ++c) {
    const float* ip = in + (size_t)(b * 3 + c) * 65536;
    for (int j = tid; j < 66 * 66; j += 256) {
      const int r = j / 66, col = j - r * 66;
      const int iy = iy0 + r, ix = ix0 + col;
      float v = 0.0f;
      if ((unsigned)iy < 256u && (unsigned)ix < 256u) v = ip[iy * 256 + ix];
      tin[c][r][col] = v;
    }
  }
  __syncthreads();
#pragma unroll
  for (int c = 0; c < 3; ++c) {
    const float* wp = wT + (size_t)c * 16 * 64 + co0;
#pragma unroll
    for (int ky = 0; ky < 4; ++ky)
#pragma unroll
      for (int kx = 0; kx < 4; ++kx) {
        const float v0 = tin[c][2 * ty + ky][2 * tx + kx];
        const float v1 = tin[c][2 * ty + ky][2 * tx + 32 + kx];
        const float v2 = tin[c][2 * ty + 32 + ky][2 * tx + kx];
        const float v3 = tin[c][2 * ty + 32 + ky][2 * tx + 32 + kx];
        const float* wk = wp + (ky * 4 + kx) * 64;
#pragma unroll
        for (int co = 0; co < 16; ++co) {
          const float wv = wk[co];
          acc[0][co] = fmaf(v0, wv, acc[0][co]);
          acc[1][co] = fmaf(v1, wv, acc[1][co]);
          acc[2][co] = fmaf(v2, wv, acc[2][co]);
          acc[3][co] = fmaf(v3, wv, acc[3][co]);
        }
      }
  }
#pragma unroll
  for (int co = 0; co < 16; ++co) {
    const float bv = bias[co0 + co];
    float* op = out + (size_t)(b * 64 + co0 + co) * 16900;
    op[(size_t)(oy0 + ty + 1) * 130 + ox0 + tx + 1]        = fmaxf(acc[0][co] + bv, 0.0f);
    op[(size_t)(oy0 + ty + 1) * 130 + ox0 + tx + 17]       = fmaxf(acc[1][co] + bv, 0.0f);
    op[(size_t)(oy0 + ty + 17) * 130 + ox0 + tx + 1]       = fmaxf(acc[2][co] + bv, 0.0f);
    op[(size_t)(oy0 + ty + 17) * 130 + ox0 + tx + 17]      = fmaxf(acc[3][co] + bv, 0.0f);
  }
}

// ---------------- conv 4x4 s2 p1, px-parallel, padded in/out, relu out (encoder) ----------
template <int NCO>
__global__ __launch_bounds__(256) void k_conv4s2_px(
    const float* __restrict__ in, const float* __restrict__ wT,
    const float* __restrict__ bias, float* __restrict__ out,
    int Cin, int Cout, int woshift, int Wp, int instride, int Wop, int outstride) {
  const int b   = blockIdx.z;
  const int co0 = blockIdx.y * NCO;
  const int px  = blockIdx.x * 256 + threadIdx.x;
  const int y = px >> woshift, x = px - (y << woshift);
  const float* ip = in + (size_t)b * Cin * instride + (size_t)(2 * y) * Wp + 2 * x;
  float acc[NCO];
#pragma unroll
  for (int co = 0; co < NCO; ++co) acc[co] = 0.0f;
  const float* wp = wT + co0;
  for (int ci = 0; ci < Cin; ++ci) {
    float v[16];
#pragma unroll
    for (int ky = 0; ky < 4; ++ky)
#pragma unroll
      for (int kx = 0; kx < 4; ++kx) v[ky * 4 + kx] = ip[ky * Wp + kx];
    ip += instride;
    const float* wk = wp;
#pragma unroll
    for (int t = 0; t < 16; ++t) {
      const float vv = v[t];
#pragma unroll
      for (int co = 0; co < NCO; ++co) acc[co] = fmaf(vv, wk[co], acc[co]);
      wk += Cout;
    }
    wp += 16 * Cout;
  }
  float* op = out + (size_t)(b * Cout + co0) * outstride + (size_t)(y + 1) * Wop + (x + 1);
#pragma unroll
  for (int co = 0; co < NCO; ++co)
    op[(size_t)co * outstride] = fmaxf(acc[co] + bias[co0 + co], 0.0f);
}

// ---------------- conv3x3 p1 (256->64 @32x32), px-parallel, relu-on-input, dense out -------
__global__ __launch_bounds__(256) void k_conv3x3_px(
    const float* __restrict__ in, const float* __restrict__ wT,
    const float* __restrict__ bias, float* __restrict__ out) {
  const int b   = blockIdx.z;
  const int co0 = blockIdx.y << 4;
  const int px  = blockIdx.x * 256 + threadIdx.x;
  const int y = px >> 5, x = px & 31;
  const float* ip = in + (size_t)b * 256 * 1156 + (size_t)y * 34 + x;
  float acc[16];
#pragma unroll
  for (int co = 0; co < 16; ++co) acc[co] = 0.0f;
  const float* wp = wT + co0;
  for (int ci = 0; ci < 256; ++ci) {
    float v[9];
#pragma unroll
    for (int dy = 0; dy < 3; ++dy)
#pragma unroll
      for (int dx = 0; dx < 3; ++dx) v[dy * 3 + dx] = fmaxf(ip[dy * 34 + dx], 0.0f);
    ip += 1156;
    const float* wk = wp;
#pragma unroll
    for (int t = 0; t < 9; ++t) {
      const float vv = v[t];
#pragma unroll
      for (int co = 0; co < 16; ++co) acc[co] = fmaf(vv, wk[co], acc[co]);
      wk += 64;
    }
    wp += 9 * 64;
  }
  float* op = out + (size_t)(b * 64 + co0) * 1024 + px;
#pragma unroll
  for (int co = 0; co < 16; ++co) op[(size_t)co * 1024] = acc[co] + bias[co0 + co];
}

// ---------------- conv1x1 px-parallel; pad-aware in/out; optional relu / residual ----------
template <int IN_RELU, int HAS_RES, int IN_PAD, int OUT_PAD>
__global__ __launch_bounds__(256) void k_conv1x1_px(
    const float* __restrict__ in, const float* __restrict__ wT,
    const float* __restrict__ bias, const float* __restrict__ res,
    float* __restrict__ out, int Cin, int Cout) {
  const int b   = blockIdx.z;
  const int co0 = blockIdx.y << 4;
  const int px  = blockIdx.x * 256 + threadIdx.x;
  const int ppad = 35 + px + 2 * (px >> 5);
  const int ioff = IN_PAD ? ppad : px;
  const int istr = IN_PAD ? 1156 : 1024;
  const int ooff = OUT_PAD ? ppad : px;
  const int ostr = OUT_PAD ? 1156 : 1024;
  float acc[16];
#pragma unroll
  for (int co = 0; co < 16; ++co) acc[co] = 0.0f;
  const float* ip = in + (size_t)b * Cin * istr + ioff;
  const float* wp = wT + co0;
  for (int ci = 0; ci < Cin; ++ci) {
    float v = *ip;
    if (IN_RELU) v = fmaxf(v, 0.0f);
    ip += istr;
#pragma unroll
    for (int co = 0; co < 16; ++co) acc[co] = fmaf(v, wp[co], acc[co]);
    wp += Cout;
  }
  float* op = out + (size_t)(b * Cout + co0) * ostr + ooff;
  const float* rp = res + (size_t)(b * Cout + co0) * ostr + ooff;
#pragma unroll
  for (int co = 0; co < 16; ++co) {
    float r = acc[co] + bias[co0 + co];
    if (HAS_RES) r += rp[(size_t)co * ostr];
    op[(size_t)co * ostr] = r;
  }
}

// ---------------- MFMA bf16 tconv (phase-decomposed implicit GEMM) ----------------
// GEMM per (batch, phase): M = W*W pixels, N = COUT, K = 4*CIN.
// Block: PXB px x COB co. 4 waves, each 32px x 32co as 2x2 16x16x32 fragments.
// A staged px-major bf16 in LDS (80B rows: 2-way bank alias = free).
// FINAL=1: fuse bias+relu+1x1(32->3) via LDS round-trip; out = dense [3][256][256].
template <int PXB, int COB, int WSHIFT, int CIN, int COUT, int WP,
          int INSTRIDE, int WOP, int OUTSTRIDE, int FINAL>
__global__ __launch_bounds__(256) void k_tconv_mfma(
    const float* __restrict__ in, const ushort_t* __restrict__ wbT,
    const float* __restrict__ bias, const float* __restrict__ ow,
    const float* __restrict__ ob, float* __restrict__ out) {
  constexpr int W = 1 << WSHIFT;
  constexpr int NCH = CIN / 8;          // K-chunks of 32 (8 ci x 4 taps)
  constexpr int PXSH = (PXB == 64) ? 6 : 7;
  constexpr int COSH = (COB == 64) ? 6 : 5;
  __shared__ __align__(16) short lsA[PXB * 40];
  __shared__ __align__(16) short lsB[COB * 40];
  __shared__ float pxco[FINAL ? PXB : 1][33];

  const int tid = threadIdx.x;
  const int b = blockIdx.z;
  const int phase = blockIdx.y & 3;
  const int ey = phase >> 1, ex = phase & 1;
  const int co_b0 = (blockIdx.y >> 2) * COB;
  const int pxb0 = blockIdx.x * PXB;

  // A staging geometry: this thread's pixel
  const int spx = tid & (PXB - 1);
  const int sy = (pxb0 + spx) >> WSHIFT;
  const int sx = (pxb0 + spx) & (W - 1);
  const float* ipa = in + (size_t)b * CIN * INSTRIDE + (size_t)(sy + ey) * WP + (sx + ex);
  // B staging geometry
  const int sco = tid & (COB - 1);
  const int skg = tid >> COSH;
  const ushort_t* wrow = wbT + ((size_t)(phase * COUT + co_b0 + sco) * CIN) * 4;

  const int lane = tid & 63, wid = tid >> 6;
  const int wm = wid % (PXB / 32), wn = wid / (PXB / 32);
  const int arow = lane & 15, ag = lane >> 4;

  f32x4 acc[2][2];
#pragma unroll
  for (int m = 0; m < 2; ++m)
#pragma unroll
    for (int n = 0; n < 2; ++n) acc[m][n] = (f32x4){0.f, 0.f, 0.f, 0.f};

  for (int ch = 0; ch < NCH; ++ch) {
    __syncthreads();
    // stage A: 8 k-values (2 ci x 4 taps) per (px, kg)
#pragma unroll
    for (int kg = tid >> PXSH; kg < 4; kg += (256 >> PXSH)) {
      const float* p = ipa + (size_t)(ch * 8 + kg * 2) * INSTRIDE;
      const float* q = p + INSTRIDE;
      u32x4 pk;
      pk[0] = (uint_t)f2b(p[0])  | ((uint_t)f2b(p[1])      << 16);
      pk[1] = (uint_t)f2b(p[WP]) | ((uint_t)f2b(p[WP + 1]) << 16);
      pk[2] = (uint_t)f2b(q[0])  | ((uint_t)f2b(q[1])      << 16);
      pk[3] = (uint_t)f2b(q[WP]) | ((uint_t)f2b(q[WP + 1]) << 16);
      *(u32x4*)(&lsA[spx * 40 + kg * 8]) = pk;
    }
    // stage B: contiguous bf16 weight row
    if (tid < COB * 4) {
      const u32x4 wv = *(const u32x4*)(wrow + ch * 32 + skg * 8);
      *(u32x4*)(&lsB[sco * 40 + skg * 8]) = wv;
    }
    __syncthreads();
    const short8 a0 = *(const short8*)(&lsA[(wm * 32 + arow) * 40 + ag * 8]);
    const short8 a1 = *(const short8*)(&lsA[(wm * 32 + 16 + arow) * 40 + ag * 8]);
    const short8 b0 = *(const short8*)(&lsB[(wn * 32 + arow) * 40 + ag * 8]);
    const short8 b1 = *(const short8*)(&lsB[(wn * 32 + 16 + arow) * 40 + ag * 8]);
    acc[0][0] = __builtin_amdgcn_mfma_f32_16x16x32_bf16(a0, b0, acc[0][0], 0, 0, 0);
    acc[0][1] = __builtin_amdgcn_mfma_f32_16x16x32_bf16(a0, b1, acc[0][1], 0, 0, 0);
    acc[1][0] = __builtin_amdgcn_mfma_f32_16x16x32_bf16(a1, b0, acc[1][0], 0, 0, 0);
    acc[1][1] = __builtin_amdgcn_mfma_f32_16x16x32_bf16(a1, b1, acc[1][1], 0, 0, 0);
  }

  if constexpr (!FINAL) {
#pragma unroll
    for (int m = 0; m < 2; ++m)
#pragma unroll
      for (int n = 0; n < 2; ++n) {
        const int col = co_b0 + wn * 32 + n * 16 + arow;
        const float bv = bias[col];
        float* obase = out + (size_t)(b * COUT + col) * OUTSTRIDE;
#pragma unroll
        for (int r = 0; r < 4; ++r) {
          const int pxl = pxb0 + wm * 32 + m * 16 + ag * 4 + r;
          const int yy = pxl >> WSHIFT, xx = pxl & (W - 1);
          obase[(size_t)(2 * yy + ey + 1) * WOP + (2 * xx + ex + 1)] =
              fmaxf(acc[m][n][r] + bv, 0.0f);
        }
      }
  } else {
#pragma unroll
    for (int m = 0; m < 2; ++m)
#pragma unroll
      for (int n = 0; n < 2; ++n) {
        const int col = wn * 32 + n * 16 + arow;
        const float bv = bias[col];
#pragma unroll
        for (int r = 0; r < 4; ++r) {
          const int pxl = wm * 32 + m * 16 + ag * 4 + r;
          pxco[pxl][col] = fmaxf(acc[m][n][r] + bv, 0.0f);
        }
      }
    __syncthreads();
    if (tid < PXB) {
      const int pxg = pxb0 + tid;
      const int yy = pxg >> WSHIFT, xx = pxg & (W - 1);
      const int oy = 2 * yy + ey, ox = 2 * xx + ex;
      float o0 = ob[0], o1 = ob[1], o2 = ob[2];
#pragma unroll
      for (int co = 0; co < 32; ++co) {
        const float v = pxco[tid][co];
        o0 = fmaf(ow[co], v, o0);
        o1 = fmaf(ow[32 + co], v, o1);
        o2 = fmaf(ow[64 + co], v, o2);
      }
      out[((size_t)(b * 3 + 0) * 256 + oy) * 256 + ox] = o0;
      out[((size_t)(b * 3 + 1) * 256 + oy) * 256 + ox] = o1;
      out[((size_t)(b * 3 + 2) * 256 + oy) * 256 + ox] = o2;
    }
  }
}

// ---------------- VQ: argmin + q gather + counts + sumsq ----------------
__global__ __launch_bounds__(256) void k_vq(
    const float* __restrict__ zlat, const float* __restrict__ cbT,
    const float* __restrict__ cnorm, const float* __restrict__ cb,
    float* __restrict__ q, float* __restrict__ counts, float* __restrict__ sumsq) {
  const int tid = threadIdx.x;
  const int px0 = blockIdx.x << 4;
  const int b   = px0 >> 10;
  const int pl0 = px0 & 1023;
  __shared__ float zT[64][17];
  __shared__ float rd[16][256];
  __shared__ int   ri[16][256];
  for (int j = tid; j < 1024; j += 256) {
    const int ci = j >> 4, p = j & 15;
    zT[ci][p] = zlat[(size_t)(b * 64 + ci) * 1024 + pl0 + p];
  }
  __syncthreads();
  float dot[4][16];
#pragma unroll
  for (int k = 0; k < 4; ++k)
#pragma unroll
    for (int p = 0; p < 16; ++p) dot[k][p] = 0.0f;
  for (int ci = 0; ci < 64; ++ci) {
    float z[16];
#pragma unroll
    for (int p = 0; p < 16; ++p) z[p] = zT[ci][p];
#pragma unroll
    for (int k = 0; k < 4; ++k) {
      const float cv = cbT[(size_t)ci * 1024 + (k << 8) + tid];
#pragma unroll
      for (int p = 0; p < 16; ++p) dot[k][p] = fmaf(cv, z[p], dot[k][p]);
    }
  }
  float bd[16]; int bi[16];
#pragma unroll
  for (int p = 0; p < 16; ++p) { bd[p] = 3.4e38f; bi[p] = 0; }
#pragma unroll
  for (int k = 0; k < 4; ++k) {
    const int c = (k << 8) + tid;
    const float cn = cnorm[c];
#pragma unroll
    for (int p = 0; p < 16; ++p) {
      const float d = cn - 2.0f * dot[k][p];
      if (d < bd[p]) { bd[p] = d; bi[p] = c; }
    }
  }
#pragma unroll
  for (int p = 0; p < 16; ++p) { rd[p][tid] = bd[p]; ri[p][tid] = bi[p]; }
  __syncthreads();
  for (int s = 128; s >= 1; s >>= 1) {
    if (tid < s) {
#pragma unroll
      for (int p = 0; p < 16; ++p) {
        const float d2 = rd[p][tid + s]; const int i2 = ri[p][tid + s];
        const float d1 = rd[p][tid];     const int i1 = ri[p][tid];
        if (d2 < d1 || (d2 == d1 && i2 < i1)) { rd[p][tid] = d2; ri[p][tid] = i2; }
      }
    }
    __syncthreads();
  }
  if (tid < 16) atomicAdd(&counts[ri[tid][0]], 1.0f);
  const int p    = tid >> 4;
  const int best = ri[p][0];
  const int cb0  = (tid & 15) << 2;
  float ss = 0.0f;
  float* qp = q + (size_t)b * 65536 + pl0 + p;
#pragma unroll
  for (int cc = 0; cc < 4; ++cc) {
    const int ci = cb0 + cc;
    const float qv = cb[(size_t)best * 64 + ci];
    const float zv = zT[ci][p];
    const float df = qv - zv;
    ss += df * df;
    qp[(size_t)ci * 1024] = qv;
  }
#pragma unroll
  for (int o = 32; o > 0; o >>= 1) ss += __shfl_down(ss, o);
  if ((tid & 63) == 0) atomicAdd(sumsq, ss);
}

__global__ void k_final(const float* __restrict__ counts, const float* __restrict__ sumsq,
                        float* __restrict__ out2) {
  const int tid = threadIdx.x;
  float h = 0.0f;
  for (int k = tid; k < 1024; k += 256) {
    const float pr = counts[k] * (1.0f / 32768.0f);
    h -= pr * logf(pr + 1e-10f);
  }
#pragma unroll
  for (int o = 32; o > 0; o >>= 1) h += __shfl_down(h, o);
  __shared__ float hs[4];
  if ((tid & 63) == 0) hs[tid >> 6] = h;
  __syncthreads();
  if (tid == 0) {
    out2[0] = 1.25f * sumsq[0] * (1.0f / 2097152.0f);
    out2[1] = expf(hs[0] + hs[1] + hs[2] + hs[3]);
  }
}

// ---------------- launcher ----------------
extern "C" void kernel_launch(void* const* d_in, const int* in_sizes, int n_in,
                              void* d_out, int out_size, void* d_ws, size_t ws_size,
                              hipStream_t stream) {
  const float* x        = (const float*)d_in[0];
  const float* enc_w0   = (const float*)d_in[1];
  const float* enc_b0   = (const float*)d_in[2];
  const float* enc_w1   = (const float*)d_in[3];
  const float* enc_b1   = (const float*)d_in[4];
  const float* enc_w2   = (const float*)d_in[5];
  const float* enc_b2   = (const float*)d_in[6];
  const float* er0w1    = (const float*)d_in[7];
  const float* er0b1    = (const float*)d_in[8];
  const float* er0w2    = (const float*)d_in[9];
  const float* er0b2    = (const float*)d_in[10];
  const float* er1w1    = (const float*)d_in[11];
  const float* er1b1    = (const float*)d_in[12];
  const float* er1w2    = (const float*)d_in[13];
  const float* er1b2    = (const float*)d_in[14];
  const float* eadj_w   = (const float*)d_in[15];
  const float* eadj_b   = (const float*)d_in[16];
  const float* codebook = (const float*)d_in[17];
  const float* dadj_w   = (const float*)d_in[18];
  const float* dadj_b   = (const float*)d_in[19];
  const float* dr0w1    = (const float*)d_in[20];
  const float* dr0b1    = (const float*)d_in[21];
  const float* dr0w2    = (const float*)d_in[22];
  const float* dr0b2    = (const float*)d_in[23];
  const float* dr1w1    = (const float*)d_in[24];
  const float* dr1b1    = (const float*)d_in[25];
  const float* dr1w2    = (const float*)d_in[26];
  const float* dr1b2    = (const float*)d_in[27];
  const float* tw0      = (const float*)d_in[28];
  const float* tb0      = (const float*)d_in[29];
  const float* tw1      = (const float*)d_in[30];
  const float* tb1      = (const float*)d_in[31];
  const float* tw2      = (const float*)d_in[32];
  const float* tb2      = (const float*)d_in[33];
  const float* out_w    = (const float*)d_in[34];
  const float* out_b    = (const float*)d_in[35];

  float* ws = (float*)d_ws;
  float* A      = ws + A_OFF;
  float* Bb     = ws + B_OFF;
  float* C      = ws + C_OFF;
  float* Dq     = ws + D_OFF;
  float* E      = ws + E_OFF;
  float* Q      = ws + Q_OFF;
  float* cbT    = ws + CBT_OFF;
  float* cnorm  = ws + CNORM_OFF;
  float* counts = ws + COUNTS_OFF;
  float* sumsq  = ws + SUMSQ_OFF;

  size_t o = WT_OFF;
  float* wt_enc0  = ws + o; o += (size_t)3 * 16 * 64;
  float* wt_enc1  = ws + o; o += (size_t)64 * 16 * 128;
  float* wt_enc2  = ws + o; o += (size_t)128 * 16 * 256;
  float* wt_er0w1 = ws + o; o += (size_t)256 * 9 * 64;
  float* wt_er0w2 = ws + o; o += (size_t)64 * 256;
  float* wt_er1w1 = ws + o; o += (size_t)256 * 9 * 64;
  float* wt_er1w2 = ws + o; o += (size_t)64 * 256;
  float* wt_eadj  = ws + o; o += (size_t)256 * 64;
  float* wt_dadj  = ws + o; o += (size_t)64 * 256;
  float* wt_dr0w1 = ws + o; o += (size_t)256 * 9 * 64;
  float* wt_dr0w2 = ws + o; o += (size_t)64 * 256;
  float* wt_dr1w1 = ws + o; o += (size_t)256 * 9 * 64;
  float* wt_dr1w2 = ws + o; o += (size_t)64 * 256;
  // bf16 tconv weights (ushort), 16B-aligned (o is a multiple of 4)
  ushort_t* wbT0 = (ushort_t*)(ws + o); o += 262144;  // 4*128*256*4 u16
  ushort_t* wbT1 = (ushort_t*)(ws + o); o += 65536;   // 4*64*128*4 u16
  ushort_t* wbT2 = (ushort_t*)(ws + o); o += 16384;   // 4*32*64*4 u16

  float* fout = (float*)d_out;

  #define GB(n) (((n) + 255) / 256)
  // zero activation region + smalls (halos + counters)
  hipMemsetAsync(ws, 0, WT_OFF * sizeof(float), stream);

  k_wt_conv<<<GB(3 * 64 * 16), 256, 0, stream>>>(enc_w0, wt_enc0, 3, 64, 16);
  k_wt_conv<<<GB(64 * 128 * 16), 256, 0, stream>>>(enc_w1, wt_enc1, 64, 128, 16);
  k_wt_conv<<<GB(128 * 256 * 16), 256, 0, stream>>>(enc_w2, wt_enc2, 128, 256, 16);
  k_wt_conv<<<GB(256 * 64 * 9), 256, 0, stream>>>(er0w1, wt_er0w1, 256, 64, 9);
  k_wt_conv<<<GB(64 * 256), 256, 0, stream>>>(er0w2, wt_er0w2, 64, 256, 1);
  k_wt_conv<<<GB(256 * 64 * 9), 256, 0, stream>>>(er1w1, wt_er1w1, 256, 64, 9);
  k_wt_conv<<<GB(64 * 256), 256, 0, stream>>>(er1w2, wt_er1w2, 64, 256, 1);
  k_wt_conv<<<GB(256 * 64), 256, 0, stream>>>(eadj_w, wt_eadj, 256, 64, 1);
  k_wt_conv<<<GB(64 * 256), 256, 0, stream>>>(dadj_w, wt_dadj, 64, 256, 1);
  k_wt_conv<<<GB(256 * 64 * 9), 256, 0, stream>>>(dr0w1, wt_dr0w1, 256, 64, 9);
  k_wt_conv<<<GB(64 * 256), 256, 0, stream>>>(dr0w2, wt_dr0w2, 64, 256, 1);
  k_wt_conv<<<GB(256 * 64 * 9), 256, 0, stream>>>(dr1w1, wt_dr1w1, 256, 64, 9);
  k_wt_conv<<<GB(64 * 256), 256, 0, stream>>>(dr1w2, wt_dr1w2, 64, 256, 1);
  k_wtb<<<GB(524288), 256, 0, stream>>>(tw0, wbT0, 256, 128);
  k_wtb<<<GB(131072), 256, 0, stream>>>(tw1, wbT1, 128, 64);
  k_wtb<<<GB(32768), 256, 0, stream>>>(tw2, wbT2, 64, 32);
  k_cbt<<<4, 256, 0, stream>>>(codebook, cbT, cnorm);

  // ---------- encoder (fp32, protects VQ numerics) ----------
  k_conv4s2_s3<<<dim3(16, 4, 32), 256, 0, stream>>>(x, wt_enc0, enc_b0, A);
  k_conv4s2_px<32><<<dim3(16, 4, 32), 256, 0, stream>>>(A, wt_enc1, enc_b1, Bb,
                                                        64, 128, 6, 130, 16900, 66, 4356);
  // A now dead -> zero C+D region (halos for enc2/res outputs)
  hipMemsetAsync(ws, 0, (size_t)18939904 * sizeof(float), stream);
  k_conv4s2_px<32><<<dim3(4, 8, 32), 256, 0, stream>>>(Bb, wt_enc2, enc_b2, C,
                                                       128, 256, 5, 66, 4356, 34, 1156);
  k_conv3x3_px<<<dim3(4, 4, 32), 256, 0, stream>>>(C, wt_er0w1, er0b1, E);
  k_conv1x1_px<1, 1, 0, 1><<<dim3(4, 16, 32), 256, 0, stream>>>(E, wt_er0w2, er0b2, C, Dq, 64, 256);
  k_conv3x3_px<<<dim3(4, 4, 32), 256, 0, stream>>>(Dq, wt_er1w1, er1b1, E);
  k_conv1x1_px<1, 1, 0, 1><<<dim3(4, 16, 32), 256, 0, stream>>>(E, wt_er1w2, er1b2, Dq, C, 64, 256);
  k_conv1x1_px<0, 0, 1, 0><<<dim3(4, 4, 32), 256, 0, stream>>>(C, wt_eadj, eadj_b, nullptr, E, 256, 64);
  // ---------- VQ (fp32 exact) ----------
  k_vq<<<2048, 256, 0, stream>>>(E, cbT, cnorm, codebook, Q, counts, sumsq);
  // ---------- decoder ----------
  k_conv1x1_px<0, 0, 0, 1><<<dim3(4, 16, 32), 256, 0, stream>>>(Q, wt_dadj, dadj_b, nullptr, C, 64, 256);
  k_conv3x3_px<<<dim3(4, 4, 32), 256, 0, stream>>>(C, wt_dr0w1, dr0b1, E);
  k_conv1x1_px<1, 1, 0, 1><<<dim3(4, 16, 32), 256, 0, stream>>>(E, wt_dr0w2, dr0b2, C, Dq, 64, 256);
  k_conv3x3_px<<<dim3(4, 4, 32), 256, 0, stream>>>(Dq, wt_dr1w1, dr1b1, E);
  k_conv1x1_px<1, 1, 0, 1><<<dim3(4, 16, 32), 256, 0, stream>>>(E, wt_dr1w2, dr1b2, Dq, C, 64, 256);
  // MFMA bf16 transposed convs (decoder only; x_recon threshold is loose)
  k_tconv_mfma<64, 64, 5, 256, 128, 34, 1156, 66, 4356, 0>
      <<<dim3(16, 8, 32), 256, 0, stream>>>(C, wbT0, tb0, nullptr, nullptr, Bb);
  // C/D/E/Q dead -> zero A region (halos for tconv1 output)
  hipMemsetAsync(ws, 0, (size_t)34611200 * sizeof(float), stream);
  k_tconv_mfma<64, 64, 6, 128, 64, 66, 4356, 130, 16900, 0>
      <<<dim3(64, 4, 32), 256, 0, stream>>>(Bb, wbT1, tb1, nullptr, nullptr, A);
  k_tconv_mfma<128, 32, 7, 64, 32, 130, 16900, 0, 0, 1>
      <<<dim3(128, 4, 32), 256, 0, stream>>>(A, wbT2, tb2, out_w, out_b, fout);
  k_final<<<1, 256, 0, stream>>>(counts, sumsq, fout + 6291456);
  #undef GB
}

// Round 8
// 2259.644 us; speedup vs baseline: 5.9590x; 1.1772x over previous
//
#include <hip/hip_runtime.h>
#include <math.h>

typedef __attribute__((ext_vector_type(4))) float f32x4;
typedef __attribute__((ext_vector_type(8))) short short8;
typedef __attribute__((ext_vector_type(4))) unsigned int u32x4;
typedef unsigned short ushort_t;
typedef unsigned int uint_t;

// ---------------- workspace layout (float offsets), lifetime-packed, PADDED activations ----
static const size_t A_OFF      = 0;
static const size_t C_OFF      = 0;
static const size_t D_OFF      = 9469952;
static const size_t E_OFF      = 18939904;
static const size_t Q_OFF      = 21037056;
static const size_t B_OFF      = 34611200;
static const size_t CBT_OFF    = 52453376;  // 64*1024
static const size_t CNORM_OFF  = 52518912;  // 1024
static const size_t COUNTS_OFF = 52519936;  // 1024
static const size_t SUMSQ_OFF  = 52520960;  // 1 (+3)
static const size_t WT_OFF     = 52520964;  // transposed weights + bf16/split weights

__device__ __forceinline__ ushort_t f2b(float f) {
  uint_t u = __float_as_uint(f);
  uint_t r = (u + 0x7FFFu + ((u >> 16) & 1u)) >> 16;
  return (ushort_t)r;
}
__device__ __forceinline__ float b2f(ushort_t h) {
  return __uint_as_float(((uint_t)h) << 16);
}

// ---------------- weight prep ----------------
// [Cout,Cin,K] -> [Cin,K,Cout]  (fp32, for fp32 kernels)
__global__ void k_wt_conv(const float* __restrict__ w, float* __restrict__ wT,
                          int Cin, int Cout, int K) {
  const int n = Cin * Cout * K;
  for (int i = blockIdx.x * 256 + threadIdx.x; i < n; i += gridDim.x * 256) {
    const int co = i % Cout;
    const int k  = (i / Cout) % K;
    const int ci = i / (Cout * K);
    wT[i] = w[((size_t)co * Cin + ci) * K + k];
  }
}
// tconv weight [Cin][Cout][16] -> bf16 wbT[phase][co][ci*4+tap]
__global__ void k_wtb(const float* __restrict__ w, ushort_t* __restrict__ wbT,
                      int Cin, int Cout) {
  const int n = 4 * Cout * Cin * 4;
  for (int i = blockIdx.x * 256 + threadIdx.x; i < n; i += gridDim.x * 256) {
    const int tap = i & 3;
    const int ci  = (i >> 2) % Cin;
    const int co  = ((i >> 2) / Cin) % Cout;
    const int ph  = (i >> 2) / (Cin * Cout);
    const int ey = ph >> 1, ex = ph & 1;
    const int ty = tap >> 1, tx = tap & 1;
    const int kidx = (3 - 2 * ty - ey) * 4 + (3 - 2 * tx - ex);
    wbT[i] = f2b(w[((size_t)ci * Cout + co) * 16 + kidx]);
  }
}
// split fp32 -> bf16 hi + bf16 lo (elementwise, layout preserved)
__global__ void k_wsplit(const float* __restrict__ w, ushort_t* __restrict__ wh,
                         ushort_t* __restrict__ wl, int n) {
  for (int i = blockIdx.x * 256 + threadIdx.x; i < n; i += gridDim.x * 256) {
    const float v = w[i];
    const ushort_t h = f2b(v);
    wh[i] = h;
    wl[i] = f2b(v - b2f(h));
  }
}
// codebook [1024,64] -> cbT [64][1024] + cnorm[1024]
__global__ void k_cbt(const float* __restrict__ cb, float* __restrict__ cbT,
                      float* __restrict__ cnorm) {
  const int c = blockIdx.x * 256 + threadIdx.x;
  float s = 0.0f;
  for (int ci = 0; ci < 64; ++ci) {
    const float v = cb[(size_t)c * 64 + ci];
    s += v * v;
    cbT[(size_t)ci * 1024 + c] = v;
  }
  cnorm[c] = s;
}

// ---------------- enc0: conv 4x4 s2 p1, Cin=3, staged, PADDED out ----------
__global__ __launch_bounds__(256) void k_conv4s2_s3(
    const float* __restrict__ in, const float* __restrict__ wT,
    const float* __restrict__ bias, float* __restrict__ out) {
  const int b   = blockIdx.z;
  const int co0 = blockIdx.y << 4;
  const int oy0 = (blockIdx.x >> 2) << 5;
  const int ox0 = (blockIdx.x & 3) << 5;
  const int tid = threadIdx.x;
  const int ty = tid >> 4, tx = tid & 15;
  __shared__ float tin[3][66][67];
  float acc[4][16];
#pragma unroll
  for (int p = 0; p < 4; ++p)
#pragma unroll
    for (int co = 0; co < 16; ++co) acc[p][co] = 0.0f;

  const int iy0 = (oy0 << 1) - 1, ix0 = (ox0 << 1) - 1;
  for (int c = 0; c < 3; ++c) {
    const float* ip = in + (size_t)(b * 3 + c) * 65536;
    for (int j = tid; j < 66 * 66; j += 256) {
      const int r = j / 66, col = j - r * 66;
      const int iy = iy0 + r, ix = ix0 + col;
      float v = 0.0f;
      if ((unsigned)iy < 256u && (unsigned)ix < 256u) v = ip[iy * 256 + ix];
      tin[c][r][col] = v;
    }
  }
  __syncthreads();
#pragma unroll
  for (int c = 0; c < 3; ++c) {
    const float* wp = wT + (size_t)c * 16 * 64 + co0;
#pragma unroll
    for (int ky = 0; ky < 4; ++ky)
#pragma unroll
      for (int kx = 0; kx < 4; ++kx) {
        const float v0 = tin[c][2 * ty + ky][2 * tx + kx];
        const float v1 = tin[c][2 * ty + ky][2 * tx + 32 + kx];
        const float v2 = tin[c][2 * ty + 32 + ky][2 * tx + kx];
        const float v3 = tin[c][2 * ty + 32 + ky][2 * tx + 32 + kx];
        const float* wk = wp + (ky * 4 + kx) * 64;
#pragma unroll
        for (int co = 0; co < 16; ++co) {
          const float wv = wk[co];
          acc[0][co] = fmaf(v0, wv, acc[0][co]);
          acc[1][co] = fmaf(v1, wv, acc[1][co]);
          acc[2][co] = fmaf(v2, wv, acc[2][co]);
          acc[3][co] = fmaf(v3, wv, acc[3][co]);
        }
      }
  }
#pragma unroll
  for (int co = 0; co < 16; ++co) {
    const float bv = bias[co0 + co];
    float* op = out + (size_t)(b * 64 + co0 + co) * 16900;
    op[(size_t)(oy0 + ty + 1) * 130 + ox0 + tx + 1]        = fmaxf(acc[0][co] + bv, 0.0f);
    op[(size_t)(oy0 + ty + 1) * 130 + ox0 + tx + 17]       = fmaxf(acc[1][co] + bv, 0.0f);
    op[(size_t)(oy0 + ty + 17) * 130 + ox0 + tx + 1]       = fmaxf(acc[2][co] + bv, 0.0f);
    op[(size_t)(oy0 + ty + 17) * 130 + ox0 + tx + 17]      = fmaxf(acc[3][co] + bv, 0.0f);
  }
}

// ---------------- split-bf16 MFMA conv 4x4 s2 p1 (encoder; ~fp32 accuracy) ----------------
// GEMM per batch: M = W*W px, N = COUT, K = CIN*16. Block 64px x 64co, 4 waves 2x2.
// acc = Ah*Bh + Ah*Bl + Al*Bh (lo*lo dropped, ~2^-18 rel). Reg-prefetch of next chunk.
template <int WSHIFT, int CIN, int COUT, int WP, int INSTRIDE, int WOP, int OUTSTRIDE>
__global__ __launch_bounds__(256) void k_conv4s2_mfma(
    const float* __restrict__ in, const ushort_t* __restrict__ wbh,
    const ushort_t* __restrict__ wbl, const float* __restrict__ bias,
    float* __restrict__ out) {
  constexpr int W = 1 << WSHIFT;
  constexpr int NCH = CIN / 2;  // K-chunk = 32 = 2 ci x 16 taps
  __shared__ __align__(16) short lsAh[64 * 40];
  __shared__ __align__(16) short lsAl[64 * 40];
  __shared__ __align__(16) short lsBh[64 * 40];
  __shared__ __align__(16) short lsBl[64 * 40];

  const int tid = threadIdx.x;
  const int b = blockIdx.z;
  const int co_b0 = blockIdx.y << 6;
  const int pxb0 = blockIdx.x << 6;

  const int spx = tid & 63;
  const int kg  = tid >> 6;     // 0..3: ci_local = kg>>1, rowpair = kg&1
  const int sy = (pxb0 + spx) >> WSHIFT;
  const int sx = (pxb0 + spx) & (W - 1);
  const float* ipa = in + (size_t)b * CIN * INSTRIDE + (size_t)(kg >> 1) * INSTRIDE
                   + (size_t)(2 * sy + 2 * (kg & 1)) * WP + 2 * sx;
  const ushort_t* wbase_h = wbh + (size_t)(co_b0 + spx) * (CIN * 16) + kg * 8;
  const ushort_t* wbase_l = wbl + (size_t)(co_b0 + spx) * (CIN * 16) + kg * 8;

  const int lane = tid & 63, wid = tid >> 6;
  const int wm = wid & 1, wn = wid >> 1;
  const int arow = lane & 15, ag = lane >> 4;

  f32x4 acc[2][2];
#pragma unroll
  for (int m = 0; m < 2; ++m)
#pragma unroll
    for (int n = 0; n < 2; ++n) acc[m][n] = (f32x4){0.f, 0.f, 0.f, 0.f};

  float pa[8];
  u32x4 pbh, pbl;
  auto loadch = [&](int ch) {
    const float* p = ipa + (size_t)ch * 2 * INSTRIDE;
    pa[0] = p[0];  pa[1] = p[1];      pa[2] = p[2];      pa[3] = p[3];
    pa[4] = p[WP]; pa[5] = p[WP + 1]; pa[6] = p[WP + 2]; pa[7] = p[WP + 3];
    pbh = *(const u32x4*)(wbase_h + (size_t)ch * 32);
    pbl = *(const u32x4*)(wbase_l + (size_t)ch * 32);
  };

  loadch(0);
  for (int ch = 0; ch < NCH; ++ch) {
    __syncthreads();
    u32x4 vh, vl;
#pragma unroll
    for (int j = 0; j < 4; ++j) {
      const ushort_t h0 = f2b(pa[2 * j]);
      const ushort_t h1 = f2b(pa[2 * j + 1]);
      const ushort_t l0 = f2b(pa[2 * j] - b2f(h0));
      const ushort_t l1 = f2b(pa[2 * j + 1] - b2f(h1));
      vh[j] = (uint_t)h0 | ((uint_t)h1 << 16);
      vl[j] = (uint_t)l0 | ((uint_t)l1 << 16);
    }
    *(u32x4*)(&lsAh[spx * 40 + kg * 8]) = vh;
    *(u32x4*)(&lsAl[spx * 40 + kg * 8]) = vl;
    *(u32x4*)(&lsBh[spx * 40 + kg * 8]) = pbh;
    *(u32x4*)(&lsBl[spx * 40 + kg * 8]) = pbl;
    if (ch + 1 < NCH) loadch(ch + 1);
    __syncthreads();
    short8 ah[2], al[2], bh[2], bl[2];
#pragma unroll
    for (int m = 0; m < 2; ++m) {
      ah[m] = *(const short8*)(&lsAh[(wm * 32 + m * 16 + arow) * 40 + ag * 8]);
      al[m] = *(const short8*)(&lsAl[(wm * 32 + m * 16 + arow) * 40 + ag * 8]);
    }
#pragma unroll
    for (int n = 0; n < 2; ++n) {
      bh[n] = *(const short8*)(&lsBh[(wn * 32 + n * 16 + arow) * 40 + ag * 8]);
      bl[n] = *(const short8*)(&lsBl[(wn * 32 + n * 16 + arow) * 40 + ag * 8]);
    }
#pragma unroll
    for (int m = 0; m < 2; ++m)
#pragma unroll
      for (int n = 0; n < 2; ++n) {
        acc[m][n] = __builtin_amdgcn_mfma_f32_16x16x32_bf16(ah[m], bh[n], acc[m][n], 0, 0, 0);
        acc[m][n] = __builtin_amdgcn_mfma_f32_16x16x32_bf16(ah[m], bl[n], acc[m][n], 0, 0, 0);
        acc[m][n] = __builtin_amdgcn_mfma_f32_16x16x32_bf16(al[m], bh[n], acc[m][n], 0, 0, 0);
      }
  }

#pragma unroll
  for (int m = 0; m < 2; ++m)
#pragma unroll
    for (int n = 0; n < 2; ++n) {
      const int col = co_b0 + wn * 32 + n * 16 + arow;
      const float bv = bias[col];
      float* obase = out + (size_t)(b * COUT + col) * OUTSTRIDE;
#pragma unroll
      for (int r = 0; r < 4; ++r) {
        const int pxl = pxb0 + wm * 32 + m * 16 + ag * 4 + r;
        const int yy = pxl >> WSHIFT, xx = pxl & (W - 1);
        obase[(size_t)(yy + 1) * WOP + (xx + 1)] = fmaxf(acc[m][n][r] + bv, 0.0f);
      }
    }
}

// ---------------- conv3x3 p1 (256->64 @32x32), px-parallel, relu-on-input, dense out -------
__global__ __launch_bounds__(256) void k_conv3x3_px(
    const float* __restrict__ in, const float* __restrict__ wT,
    const float* __restrict__ bias, float* __restrict__ out) {
  const int b   = blockIdx.z;
  const int co0 = blockIdx.y << 4;
  const int px  = blockIdx.x * 256 + threadIdx.x;
  const int y = px >> 5, x = px & 31;
  const float* ip = in + (size_t)b * 256 * 1156 + (size_t)y * 34 + x;
  float acc[16];
#pragma unroll
  for (int co = 0; co < 16; ++co) acc[co] = 0.0f;
  const float* wp = wT + co0;
  for (int ci = 0; ci < 256; ++ci) {
    float v[9];
#pragma unroll
    for (int dy = 0; dy < 3; ++dy)
#pragma unroll
      for (int dx = 0; dx < 3; ++dx) v[dy * 3 + dx] = fmaxf(ip[dy * 34 + dx], 0.0f);
    ip += 1156;
    const float* wk = wp;
#pragma unroll
    for (int t = 0; t < 9; ++t) {
      const float vv = v[t];
#pragma unroll
      for (int co = 0; co < 16; ++co) acc[co] = fmaf(vv, wk[co], acc[co]);
      wk += 64;
    }
    wp += 9 * 64;
  }
  float* op = out + (size_t)(b * 64 + co0) * 1024 + px;
#pragma unroll
  for (int co = 0; co < 16; ++co) op[(size_t)co * 1024] = acc[co] + bias[co0 + co];
}

// ---------------- conv1x1 px-parallel; pad-aware in/out; optional relu / residual ----------
template <int IN_RELU, int HAS_RES, int IN_PAD, int OUT_PAD>
__global__ __launch_bounds__(256) void k_conv1x1_px(
    const float* __restrict__ in, const float* __restrict__ wT,
    const float* __restrict__ bias, const float* __restrict__ res,
    float* __restrict__ out, int Cin, int Cout) {
  const int b   = blockIdx.z;
  const int co0 = blockIdx.y << 4;
  const int px  = blockIdx.x * 256 + threadIdx.x;
  const int ppad = 35 + px + 2 * (px >> 5);
  const int ioff = IN_PAD ? ppad : px;
  const int istr = IN_PAD ? 1156 : 1024;
  const int ooff = OUT_PAD ? ppad : px;
  const int ostr = OUT_PAD ? 1156 : 1024;
  float acc[16];
#pragma unroll
  for (int co = 0; co < 16; ++co) acc[co] = 0.0f;
  const float* ip = in + (size_t)b * Cin * istr + ioff;
  const float* wp = wT + co0;
  for (int ci = 0; ci < Cin; ++ci) {
    float v = *ip;
    if (IN_RELU) v = fmaxf(v, 0.0f);
    ip += istr;
#pragma unroll
    for (int co = 0; co < 16; ++co) acc[co] = fmaf(v, wp[co], acc[co]);
    wp += Cout;
  }
  float* op = out + (size_t)(b * Cout + co0) * ostr + ooff;
  const float* rp = res + (size_t)(b * Cout + co0) * ostr + ooff;
#pragma unroll
  for (int co = 0; co < 16; ++co) {
    float r = acc[co] + bias[co0 + co];
    if (HAS_RES) r += rp[(size_t)co * ostr];
    op[(size_t)co * ostr] = r;
  }
}

// ---------------- MFMA bf16 tconv (phase-decomposed implicit GEMM), reg-prefetch -----------
template <int PXB, int COB, int WSHIFT, int CIN, int COUT, int WP,
          int INSTRIDE, int WOP, int OUTSTRIDE, int FINAL>
__global__ __launch_bounds__(256) void k_tconv_mfma(
    const float* __restrict__ in, const ushort_t* __restrict__ wbT,
    const float* __restrict__ bias, const float* __restrict__ ow,
    const float* __restrict__ ob, float* __restrict__ out) {
  constexpr int W = 1 << WSHIFT;
  constexpr int NCH = CIN / 8;          // K-chunks of 32 (8 ci x 4 taps)
  constexpr int PXSH = (PXB == 64) ? 6 : 7;
  constexpr int COSH = (COB == 64) ? 6 : 5;
  constexpr int NKG = (PXB * 4) / 256;  // 1 or 2
  constexpr int KGSTEP = 256 / PXB;     // 4 or 2
  __shared__ __align__(16) short lsA[PXB * 40];
  __shared__ __align__(16) short lsB[COB * 40];
  __shared__ float pxco[FINAL ? PXB : 1][33];

  const int tid = threadIdx.x;
  const int b = blockIdx.z;
  const int phase = blockIdx.y & 3;
  const int ey = phase >> 1, ex = phase & 1;
  const int co_b0 = (blockIdx.y >> 2) * COB;
  const int pxb0 = blockIdx.x * PXB;

  const int spx = tid & (PXB - 1);
  const int kg0 = tid >> PXSH;
  const int sy = (pxb0 + spx) >> WSHIFT;
  const int sx = (pxb0 + spx) & (W - 1);
  const float* ipa = in + (size_t)b * CIN * INSTRIDE + (size_t)(sy + ey) * WP + (sx + ex);
  const int sco = tid & (COB - 1);
  const int skg = tid >> COSH;
  const bool bstage = (tid < COB * 4);
  const ushort_t* wrow = wbT + ((size_t)(phase * COUT + co_b0 + sco) * CIN) * 4;

  const int lane = tid & 63, wid = tid >> 6;
  const int wm = wid % (PXB / 32), wn = wid / (PXB / 32);
  const int arow = lane & 15, ag = lane >> 4;

  f32x4 acc[2][2];
#pragma unroll
  for (int m = 0; m < 2; ++m)
#pragma unroll
    for (int n = 0; n < 2; ++n) acc[m][n] = (f32x4){0.f, 0.f, 0.f, 0.f};

  float pa0[8], pa1[8];
  u32x4 pb;
  auto loadch = [&](int ch) {
    { const float* p = ipa + (size_t)(ch * 8 + kg0 * 2) * INSTRIDE;
      const float* q = p + INSTRIDE;
      pa0[0] = p[0]; pa0[1] = p[1]; pa0[2] = p[WP]; pa0[3] = p[WP + 1];
      pa0[4] = q[0]; pa0[5] = q[1]; pa0[6] = q[WP]; pa0[7] = q[WP + 1]; }
    if constexpr (NKG == 2) {
      const float* p = ipa + (size_t)(ch * 8 + (kg0 + KGSTEP) * 2) * INSTRIDE;
      const float* q = p + INSTRIDE;
      pa1[0] = p[0]; pa1[1] = p[1]; pa1[2] = p[WP]; pa1[3] = p[WP + 1];
      pa1[4] = q[0]; pa1[5] = q[1]; pa1[6] = q[WP]; pa1[7] = q[WP + 1]; }
    if (bstage) pb = *(const u32x4*)(wrow + ch * 32 + skg * 8);
  };

  loadch(0);
  for (int ch = 0; ch < NCH; ++ch) {
    __syncthreads();
    { u32x4 pk;
      pk[0] = (uint_t)f2b(pa0[0]) | ((uint_t)f2b(pa0[1]) << 16);
      pk[1] = (uint_t)f2b(pa0[2]) | ((uint_t)f2b(pa0[3]) << 16);
      pk[2] = (uint_t)f2b(pa0[4]) | ((uint_t)f2b(pa0[5]) << 16);
      pk[3] = (uint_t)f2b(pa0[6]) | ((uint_t)f2b(pa0[7]) << 16);
      *(u32x4*)(&lsA[spx * 40 + kg0 * 8]) = pk; }
    if constexpr (NKG == 2) {
      u32x4 pk;
      pk[0] = (uint_t)f2b(pa1[0]) | ((uint_t)f2b(pa1[1]) << 16);
      pk[1] = (uint_t)f2b(pa1[2]) | ((uint_t)f2b(pa1[3]) << 16);
      pk[2] = (uint_t)f2b(pa1[4]) | ((uint_t)f2b(pa1[5]) << 16);
      pk[3] = (uint_t)f2b(pa1[6]) | ((uint_t)f2b(pa1[7]) << 16);
      *(u32x4*)(&lsA[spx * 40 + (kg0 + KGSTEP) * 8]) = pk;
    }
    if (bstage) *(u32x4*)(&lsB[sco * 40 + skg * 8]) = pb;
    if (ch + 1 < NCH) loadch(ch + 1);
    __syncthreads();
    const short8 a0 = *(const short8*)(&lsA[(wm * 32 + arow) * 40 + ag * 8]);
    const short8 a1 = *(const short8*)(&lsA[(wm * 32 + 16 + arow) * 40 + ag * 8]);
    const short8 b0 = *(const short8*)(&lsB[(wn * 32 + arow) * 40 + ag * 8]);
    const short8 b1 = *(const short8*)(&lsB[(wn * 32 + 16 + arow) * 40 + ag * 8]);
    acc[0][0] = __builtin_amdgcn_mfma_f32_16x16x32_bf16(a0, b0, acc[0][0], 0, 0, 0);
    acc[0][1] = __builtin_amdgcn_mfma_f32_16x16x32_bf16(a0, b1, acc[0][1], 0, 0, 0);
    acc[1][0] = __builtin_amdgcn_mfma_f32_16x16x32_bf16(a1, b0, acc[1][0], 0, 0, 0);
    acc[1][1] = __builtin_amdgcn_mfma_f32_16x16x32_bf16(a1, b1, acc[1][1], 0, 0, 0);
  }

  if constexpr (!FINAL) {
#pragma unroll
    for (int m = 0; m < 2; ++m)
#pragma unroll
      for (int n = 0; n < 2; ++n) {
        const int col = co_b0 + wn * 32 + n * 16 + arow;
        const float bv = bias[col];
        float* obase = out + (size_t)(b * COUT + col) * OUTSTRIDE;
#pragma unroll
        for (int r = 0; r < 4; ++r) {
          const int pxl = pxb0 + wm * 32 + m * 16 + ag * 4 + r;
          const int yy = pxl >> WSHIFT, xx = pxl & (W - 1);
          obase[(size_t)(2 * yy + ey + 1) * WOP + (2 * xx + ex + 1)] =
              fmaxf(acc[m][n][r] + bv, 0.0f);
        }
      }
  } else {
#pragma unroll
    for (int m = 0; m < 2; ++m)
#pragma unroll
      for (int n = 0; n < 2; ++n) {
        const int col = wn * 32 + n * 16 + arow;
        const float bv = bias[col];
#pragma unroll
        for (int r = 0; r < 4; ++r) {
          const int pxl = wm * 32 + m * 16 + ag * 4 + r;
          pxco[pxl][col] = fmaxf(acc[m][n][r] + bv, 0.0f);
        }
      }
    __syncthreads();
    if (tid < PXB) {
      const int pxg = pxb0 + tid;
      const int yy = pxg >> WSHIFT, xx = pxg & (W - 1);
      const int oy = 2 * yy + ey, ox = 2 * xx + ex;
      float o0 = ob[0], o1 = ob[1], o2 = ob[2];
#pragma unroll
      for (int co = 0; co < 32; ++co) {
        const float v = pxco[tid][co];
        o0 = fmaf(ow[co], v, o0);
        o1 = fmaf(ow[32 + co], v, o1);
        o2 = fmaf(ow[64 + co], v, o2);
      }
      out[((size_t)(b * 3 + 0) * 256 + oy) * 256 + ox] = o0;
      out[((size_t)(b * 3 + 1) * 256 + oy) * 256 + ox] = o1;
      out[((size_t)(b * 3 + 2) * 256 + oy) * 256 + ox] = o2;
    }
  }
}

// ---------------- VQ: argmin + q gather + counts + sumsq ----------------
__global__ __launch_bounds__(256) void k_vq(
    const float* __restrict__ zlat, const float* __restrict__ cbT,
    const float* __restrict__ cnorm, const float* __restrict__ cb,
    float* __restrict__ q, float* __restrict__ counts, float* __restrict__ sumsq) {
  const int tid = threadIdx.x;
  const int px0 = blockIdx.x << 4;
  const int b   = px0 >> 10;
  const int pl0 = px0 & 1023;
  __shared__ float zT[64][17];
  __shared__ float rd[16][256];
  __shared__ int   ri[16][256];
  for (int j = tid; j < 1024; j += 256) {
    const int ci = j >> 4, p = j & 15;
    zT[ci][p] = zlat[(size_t)(b * 64 + ci) * 1024 + pl0 + p];
  }
  __syncthreads();
  float dot[4][16];
#pragma unroll
  for (int k = 0; k < 4; ++k)
#pragma unroll
    for (int p = 0; p < 16; ++p) dot[k][p] = 0.0f;
  for (int ci = 0; ci < 64; ++ci) {
    float z[16];
#pragma unroll
    for (int p = 0; p < 16; ++p) z[p] = zT[ci][p];
#pragma unroll
    for (int k = 0; k < 4; ++k) {
      const float cv = cbT[(size_t)ci * 1024 + (k << 8) + tid];
#pragma unroll
      for (int p = 0; p < 16; ++p) dot[k][p] = fmaf(cv, z[p], dot[k][p]);
    }
  }
  float bd[16]; int bi[16];
#pragma unroll
  for (int p = 0; p < 16; ++p) { bd[p] = 3.4e38f; bi[p] = 0; }
#pragma unroll
  for (int k = 0; k < 4; ++k) {
    const int c = (k << 8) + tid;
    const float cn = cnorm[c];
#pragma unroll
    for (int p = 0; p < 16; ++p) {
      const float d = cn - 2.0f * dot[k][p];
      if (d < bd[p]) { bd[p] = d; bi[p] = c; }
    }
  }
#pragma unroll
  for (int p = 0; p < 16; ++p) { rd[p][tid] = bd[p]; ri[p][tid] = bi[p]; }
  __syncthreads();
  for (int s = 128; s >= 1; s >>= 1) {
    if (tid < s) {
#pragma unroll
      for (int p = 0; p < 16; ++p) {
        const float d2 = rd[p][tid + s]; const int i2 = ri[p][tid + s];
        const float d1 = rd[p][tid];     const int i1 = ri[p][tid];
        if (d2 < d1 || (d2 == d1 && i2 < i1)) { rd[p][tid] = d2; ri[p][tid] = i2; }
      }
    }
    __syncthreads();
  }
  if (tid < 16) atomicAdd(&counts[ri[tid][0]], 1.0f);
  const int p    = tid >> 4;
  const int best = ri[p][0];
  const int cb0  = (tid & 15) << 2;
  float ss = 0.0f;
  float* qp = q + (size_t)b * 65536 + pl0 + p;
#pragma unroll
  for (int cc = 0; cc < 4; ++cc) {
    const int ci = cb0 + cc;
    const float qv = cb[(size_t)best * 64 + ci];
    const float zv = zT[ci][p];
    const float df = qv - zv;
    ss += df * df;
    qp[(size_t)ci * 1024] = qv;
  }
#pragma unroll
  for (int o = 32; o > 0; o >>= 1) ss += __shfl_down(ss, o);
  if ((tid & 63) == 0) atomicAdd(sumsq, ss);
}

__global__ void k_final(const float* __restrict__ counts, const float* __restrict__ sumsq,
                        float* __restrict__ out2) {
  const int tid = threadIdx.x;
  float h = 0.0f;
  for (int k = tid; k < 1024; k += 256) {
    const float pr = counts[k] * (1.0f / 32768.0f);
    h -= pr * logf(pr + 1e-10f);
  }
#pragma unroll
  for (int o = 32; o > 0; o >>= 1) h += __shfl_down(h, o);
  __shared__ float hs[4];
  if ((tid & 63) == 0) hs[tid >> 6] = h;
  __syncthreads();
  if (tid == 0) {
    out2[0] = 1.25f * sumsq[0] * (1.0f / 2097152.0f);
    out2[1] = expf(hs[0] + hs[1] + hs[2] + hs[3]);
  }
}

// ---------------- launcher ----------------
extern "C" void kernel_launch(void* const* d_in, const int* in_sizes, int n_in,
                              void* d_out, int out_size, void* d_ws, size_t ws_size,
                              hipStream_t stream) {
  const float* x        = (const float*)d_in[0];
  const float* enc_w0   = (const float*)d_in[1];
  const float* enc_b0   = (const float*)d_in[2];
  const float* enc_w1   = (const float*)d_in[3];
  const float* enc_b1   = (const float*)d_in[4];
  const float* enc_w2   = (const float*)d_in[5];
  const float* enc_b2   = (const float*)d_in[6];
  const float* er0w1    = (const float*)d_in[7];
  const float* er0b1    = (const float*)d_in[8];
  const float* er0w2    = (const float*)d_in[9];
  const float* er0b2    = (const float*)d_in[10];
  const float* er1w1    = (const float*)d_in[11];
  const float* er1b1    = (const float*)d_in[12];
  const float* er1w2    = (const float*)d_in[13];
  const float* er1b2    = (const float*)d_in[14];
  const float* eadj_w   = (const float*)d_in[15];
  const float* eadj_b   = (const float*)d_in[16];
  const float* codebook = (const float*)d_in[17];
  const float* dadj_w   = (const float*)d_in[18];
  const float* dadj_b   = (const float*)d_in[19];
  const float* dr0w1    = (const float*)d_in[20];
  const float* dr0b1    = (const float*)d_in[21];
  const float* dr0w2    = (const float*)d_in[22];
  const float* dr0b2    = (const float*)d_in[23];
  const float* dr1w1    = (const float*)d_in[24];
  const float* dr1b1    = (const float*)d_in[25];
  const float* dr1w2    = (const float*)d_in[26];
  const float* dr1b2    = (const float*)d_in[27];
  const float* tw0      = (const float*)d_in[28];
  const float* tb0      = (const float*)d_in[29];
  const float* tw1      = (const float*)d_in[30];
  const float* tb1      = (const float*)d_in[31];
  const float* tw2      = (const float*)d_in[32];
  const float* tb2      = (const float*)d_in[33];
  const float* out_w    = (const float*)d_in[34];
  const float* out_b    = (const float*)d_in[35];

  float* ws = (float*)d_ws;
  float* A      = ws + A_OFF;
  float* Bb     = ws + B_OFF;
  float* C      = ws + C_OFF;
  float* Dq     = ws + D_OFF;
  float* E      = ws + E_OFF;
  float* Q      = ws + Q_OFF;
  float* cbT    = ws + CBT_OFF;
  float* cnorm  = ws + CNORM_OFF;
  float* counts = ws + COUNTS_OFF;
  float* sumsq  = ws + SUMSQ_OFF;

  size_t o = WT_OFF;
  float* wt_enc0  = ws + o; o += (size_t)3 * 16 * 64;
  float* wt_er0w1 = ws + o; o += (size_t)256 * 9 * 64;
  float* wt_er0w2 = ws + o; o += (size_t)64 * 256;
  float* wt_er1w1 = ws + o; o += (size_t)256 * 9 * 64;
  float* wt_er1w2 = ws + o; o += (size_t)64 * 256;
  float* wt_eadj  = ws + o; o += (size_t)256 * 64;
  float* wt_dadj  = ws + o; o += (size_t)64 * 256;
  float* wt_dr0w1 = ws + o; o += (size_t)256 * 9 * 64;
  float* wt_dr0w2 = ws + o; o += (size_t)64 * 256;
  float* wt_dr1w1 = ws + o; o += (size_t)256 * 9 * 64;
  float* wt_dr1w2 = ws + o; o += (size_t)64 * 256;
  // bf16 tconv weights
  ushort_t* wbT0 = (ushort_t*)(ws + o); o += 131072;  // 4*128*256*4 u16
  ushort_t* wbT1 = (ushort_t*)(ws + o); o += 32768;   // 4*64*128*4 u16
  ushort_t* wbT2 = (ushort_t*)(ws + o); o += 8192;    // 4*32*64*4 u16
  // split bf16 encoder conv weights (layout [co][ci][16] preserved)
  ushort_t* wsh1 = (ushort_t*)(ws + o); o += 65536;   // 128*64*16 u16
  ushort_t* wsl1 = (ushort_t*)(ws + o); o += 65536;
  ushort_t* wsh2 = (ushort_t*)(ws + o); o += 262144;  // 256*128*16 u16
  ushort_t* wsl2 = (ushort_t*)(ws + o); o += 262144;

  float* fout = (float*)d_out;

  #define GB(n) (((n) + 255) / 256)
  // zero activation region + smalls (halos + counters)
  hipMemsetAsync(ws, 0, WT_OFF * sizeof(float), stream);

  k_wt_conv<<<GB(3 * 64 * 16), 256, 0, stream>>>(enc_w0, wt_enc0, 3, 64, 16);
  k_wt_conv<<<GB(256 * 64 * 9), 256, 0, stream>>>(er0w1, wt_er0w1, 256, 64, 9);
  k_wt_conv<<<GB(64 * 256), 256, 0, stream>>>(er0w2, wt_er0w2, 64, 256, 1);
  k_wt_conv<<<GB(256 * 64 * 9), 256, 0, stream>>>(er1w1, wt_er1w1, 256, 64, 9);
  k_wt_conv<<<GB(64 * 256), 256, 0, stream>>>(er1w2, wt_er1w2, 64, 256, 1);
  k_wt_conv<<<GB(256 * 64), 256, 0, stream>>>(eadj_w, wt_eadj, 256, 64, 1);
  k_wt_conv<<<GB(64 * 256), 256, 0, stream>>>(dadj_w, wt_dadj, 64, 256, 1);
  k_wt_conv<<<GB(256 * 64 * 9), 256, 0, stream>>>(dr0w1, wt_dr0w1, 256, 64, 9);
  k_wt_conv<<<GB(64 * 256), 256, 0, stream>>>(dr0w2, wt_dr0w2, 64, 256, 1);
  k_wt_conv<<<GB(256 * 64 * 9), 256, 0, stream>>>(dr1w1, wt_dr1w1, 256, 64, 9);
  k_wt_conv<<<GB(64 * 256), 256, 0, stream>>>(dr1w2, wt_dr1w2, 64, 256, 1);
  k_wtb<<<GB(524288), 256, 0, stream>>>(tw0, wbT0, 256, 128);
  k_wtb<<<GB(131072), 256, 0, stream>>>(tw1, wbT1, 128, 64);
  k_wtb<<<GB(32768), 256, 0, stream>>>(tw2, wbT2, 64, 32);
  k_wsplit<<<GB(131072), 256, 0, stream>>>(enc_w1, wsh1, wsl1, 131072);
  k_wsplit<<<GB(524288), 256, 0, stream>>>(enc_w2, wsh2, wsl2, 524288);
  k_cbt<<<4, 256, 0, stream>>>(codebook, cbT, cnorm);

  // ---------- encoder (split-bf16 MFMA ~ fp32 accuracy; protects VQ argmin) ----------
  k_conv4s2_s3<<<dim3(16, 4, 32), 256, 0, stream>>>(x, wt_enc0, enc_b0, A);
  k_conv4s2_mfma<6, 64, 128, 130, 16900, 66, 4356>
      <<<dim3(64, 2, 32), 256, 0, stream>>>(A, wsh1, wsl1, enc_b1, Bb);
  // A now dead -> zero C+D region (halos for enc2/res outputs)
  hipMemsetAsync(ws, 0, (size_t)18939904 * sizeof(float), stream);
  k_conv4s2_mfma<5, 128, 256, 66, 4356, 34, 1156>
      <<<dim3(16, 4, 32), 256, 0, stream>>>(Bb, wsh2, wsl2, enc_b2, C);
  k_conv3x3_px<<<dim3(4, 4, 32), 256, 0, stream>>>(C, wt_er0w1, er0b1, E);
  k_conv1x1_px<1, 1, 0, 1><<<dim3(4, 16, 32), 256, 0, stream>>>(E, wt_er0w2, er0b2, C, Dq, 64, 256);
  k_conv3x3_px<<<dim3(4, 4, 32), 256, 0, stream>>>(Dq, wt_er1w1, er1b1, E);
  k_conv1x1_px<1, 1, 0, 1><<<dim3(4, 16, 32), 256, 0, stream>>>(E, wt_er1w2, er1b2, Dq, C, 64, 256);
  k_conv1x1_px<0, 0, 1, 0><<<dim3(4, 4, 32), 256, 0, stream>>>(C, wt_eadj, eadj_b, nullptr, E, 256, 64);
  // ---------- VQ (fp32 exact) ----------
  k_vq<<<2048, 256, 0, stream>>>(E, cbT, cnorm, codebook, Q, counts, sumsq);
  // ---------- decoder ----------
  k_conv1x1_px<0, 0, 0, 1><<<dim3(4, 16, 32), 256, 0, stream>>>(Q, wt_dadj, dadj_b, nullptr, C, 64, 256);
  k_conv3x3_px<<<dim3(4, 4, 32), 256, 0, stream>>>(C, wt_dr0w1, dr0b1, E);
  k_conv1x1_px<1, 1, 0, 1><<<dim3(4, 16, 32), 256, 0, stream>>>(E, wt_dr0w2, dr0b2, C, Dq, 64, 256);
  k_conv3x3_px<<<dim3(4, 4, 32), 256, 0, stream>>>(Dq, wt_dr1w1, dr1b1, E);
  k_conv1x1_px<1, 1, 0, 1><<<dim3(4, 16, 32), 256, 0, stream>>>(E, wt_dr1w2, dr1b2, Dq, C, 64, 256);
  // MFMA bf16 transposed convs (decoder only; x_recon threshold is loose)
  k_tconv_mfma<64, 64, 5, 256, 128, 34, 1156, 66, 4356, 0>
      <<<dim3(16, 8, 32), 256, 0, stream>>>(C, wbT0, tb0, nullptr, nullptr, Bb);
  // C/D/E/Q dead -> zero A region (halos for tconv1 output)
  hipMemsetAsync(ws, 0, (size_t)34611200 * sizeof(float), stream);
  k_tconv_mfma<64, 64, 6, 128, 64, 66, 4356, 130, 16900, 0>
      <<<dim3(64, 4, 32), 256, 0, stream>>>(Bb, wbT1, tb1, nullptr, nullptr, A);
  k_tconv_mfma<128, 32, 7, 64, 32, 130, 16900, 0, 0, 1>
      <<<dim3(128, 4, 32), 256, 0, stream>>>(A, wbT2, tb2, out_w, out_b, fout);
  k_final<<<1, 256, 0, stream>>>(counts, sumsq, fout + 6291456);
  #undef GB
}